// Round 1
// baseline (949.985 us; speedup 1.0000x reference)
//
#include <hip/hip_runtime.h>

#define NN 4096
#define F_IN 1024
#define NHEAD 8
#define NCLS 40
#define LRA 0.2f
#define NWRD 128   // bitmask words per row (4096/32)

__device__ __forceinline__ float lrelu(float x){ return x > 0.f ? x : LRA*x; }

// ---------------- pack adjacency int32 -> bitmask ----------------
__global__ __launch_bounds__(256) void pack_adj_k(const int* __restrict__ adj, unsigned int* __restrict__ bm){
  int gid = blockIdx.x*256 + threadIdx.x;
  int lane = threadIdx.x & 63;
  unsigned long long m = __ballot(adj[gid] > 0);
  if (lane == 0)       bm[gid >> 5] = (unsigned int)m;
  else if (lane == 32) bm[gid >> 5] = (unsigned int)(m >> 32);
}

// ---------------- Whc[n][h*64+o] = x @ W  (fp32 tiled GEMM, BM=BN=64, BK=16) ----------------
__global__ __launch_bounds__(256) void gemm_wh_k(const float* __restrict__ x, const float* __restrict__ W,
                                                 float* __restrict__ Whc){
  __shared__ float As[16][64];
  __shared__ float Bs[16][64];
  const int t = threadIdx.x;
  const int bx = blockIdx.x, h = blockIdx.y;
  const int tx = t & 15, ty = t >> 4;
  const int am = t >> 2, ak = (t & 3) << 2;
  const int bk = t >> 4, bn = (t & 15) << 2;
  const float* Wh_ = W + (size_t)h*F_IN*64;
  const float* xp  = x + (size_t)(bx*64 + am)*F_IN + ak;
  float acc[4][4] = {};
  for (int k0 = 0; k0 < F_IN; k0 += 16){
    float4 av = *(const float4*)(xp + k0);
    float4 bv = *(const float4*)(Wh_ + (size_t)(k0 + bk)*64 + bn);
    __syncthreads();
    As[ak+0][am]=av.x; As[ak+1][am]=av.y; As[ak+2][am]=av.z; As[ak+3][am]=av.w;
    *(float4*)&Bs[bk][bn] = bv;
    __syncthreads();
    #pragma unroll
    for (int k = 0; k < 16; ++k){
      float4 a = *(const float4*)&As[k][ty<<2];
      float4 b = *(const float4*)&Bs[k][tx<<2];
      acc[0][0]=fmaf(a.x,b.x,acc[0][0]); acc[0][1]=fmaf(a.x,b.y,acc[0][1]); acc[0][2]=fmaf(a.x,b.z,acc[0][2]); acc[0][3]=fmaf(a.x,b.w,acc[0][3]);
      acc[1][0]=fmaf(a.y,b.x,acc[1][0]); acc[1][1]=fmaf(a.y,b.y,acc[1][1]); acc[1][2]=fmaf(a.y,b.z,acc[1][2]); acc[1][3]=fmaf(a.y,b.w,acc[1][3]);
      acc[2][0]=fmaf(a.z,b.x,acc[2][0]); acc[2][1]=fmaf(a.z,b.y,acc[2][1]); acc[2][2]=fmaf(a.z,b.z,acc[2][2]); acc[2][3]=fmaf(a.z,b.w,acc[2][3]);
      acc[3][0]=fmaf(a.w,b.x,acc[3][0]); acc[3][1]=fmaf(a.w,b.y,acc[3][1]); acc[3][2]=fmaf(a.w,b.z,acc[3][2]); acc[3][3]=fmaf(a.w,b.w,acc[3][3]);
    }
  }
  #pragma unroll
  for (int r = 0; r < 4; ++r){
    float4 o = make_float4(acc[r][0],acc[r][1],acc[r][2],acc[r][3]);
    *(float4*)&Whc[(size_t)(bx*64 + (ty<<2) + r)*512 + h*64 + (tx<<2)] = o;
  }
}

// ---------------- src[h][n], dst[h][n] = <Wh[h][n][:], a_src/a_dst[h][:]> ----------------
__global__ __launch_bounds__(512) void src_dst_k(const float* __restrict__ Whc,
                                                 const float* __restrict__ a_src, const float* __restrict__ a_dst,
                                                 float* __restrict__ srcv, float* __restrict__ dstv){
  const int n = blockIdx.x;
  const int h = threadIdx.x >> 6, o = threadIdx.x & 63;
  float v  = Whc[(size_t)n*512 + h*64 + o];
  float ps = v * a_src[h*64 + o];
  float pd = v * a_dst[h*64 + o];
  #pragma unroll
  for (int off = 32; off; off >>= 1){ ps += __shfl_down(ps, off); pd += __shfl_down(pd, off); }
  if (o == 0){ srcv[h*NN + n] = ps; dstv[h*NN + n] = pd; }
}

// ---------------- maxd[h][i] = max over neighbors j of dst[h][j] (one wave per row) ----------------
__global__ __launch_bounds__(256) void row_max_k(const unsigned int* __restrict__ bm,
                                                 const float* __restrict__ dstv, float* __restrict__ maxd,
                                                 int total){
  const int wid = (blockIdx.x*256 + threadIdx.x) >> 6;
  if (wid >= total) return;
  const int lane = threadIdx.x & 63;
  const int h = wid >> 12, i = wid & (NN - 1);
  const float* dh = dstv + (size_t)h*NN;
  const unsigned int* row = bm + (size_t)i*NWRD;
  float m = -3.0e38f;
  for (int j0 = 0; j0 < NN; j0 += 64){
    unsigned int w = row[(j0 >> 5) + (lane >> 5)];
    if ((w >> (lane & 31)) & 1u) m = fmaxf(m, dh[j0 + lane]);
  }
  #pragma unroll
  for (int off = 32; off; off >>= 1) m = fmaxf(m, __shfl_xor(m, off));
  if (lane == 0) maxd[wid] = m;
}

// ---------------- masked-softmax aggregate: out[i] = (sum_j w_ij * V[j]) / sum_j w_ij ----------------
// Block: 32 rows (i0..i0+31) x one head; j tiled by 64. 4 waves, each 8 rows; lane=(g,c): 2 rows x 4 cols.
template<int NCOL, int VSTR, int OSTR, bool DO_ELU>
__global__ __launch_bounds__(256) void aggregate_k(const unsigned int* __restrict__ bm,
                                                   const float* __restrict__ Whv,
                                                   const float* __restrict__ srcv, const float* __restrict__ dstv,
                                                   const float* __restrict__ maxd, float* __restrict__ outp){
  constexpr int NCG = NCOL/4;
  __shared__ float WhS[64][NCOL];
  __shared__ float wt[32][65];          // +1 pad: conflict-free broadcast reads
  __shared__ float dS[64];
  __shared__ float sS[32], mS[32];
  __shared__ unsigned int bitS[32][2];
  const int t = threadIdx.x;
  const int h = blockIdx.y;
  const int i0 = blockIdx.x << 5;
  const int lane = t & 63, wv = t >> 6;
  const int g = lane >> 4, c = lane & 15;
  const int cc = (c < NCG) ? c : 0;
  const int rl = (wv << 3) + (g << 1);  // local row for rr=0 (rr=1 is rl+1)
  if (t < 32){
    float s = srcv[(size_t)h*NN + i0 + t];
    sS[t] = s;
    mS[t] = lrelu(s + maxd[(size_t)h*NN + i0 + t]);
  }
  float4 a0 = make_float4(0,0,0,0), a1 = make_float4(0,0,0,0);
  float sw0 = 0.f, sw1 = 0.f;
  for (int jt = 0; jt < NN/64; ++jt){
    const int j0 = jt << 6;
    __syncthreads();
    for (int idx = t; idx < 64*NCG; idx += 256){
      int j = idx / NCG, q = idx - j*NCG;
      *(float4*)&WhS[j][q<<2] = *(const float4*)&Whv[(size_t)(j0+j)*VSTR + h*64 + (q<<2)];
    }
    if (t < 64) dS[t] = dstv[(size_t)h*NN + j0 + t];
    if (t < 64) bitS[t>>1][t&1] = bm[(size_t)(i0 + (t>>1))*NWRD + (jt<<1) + (t&1)];
    __syncthreads();
    #pragma unroll
    for (int kk = 0; kk < 8; ++kk){       // 32x64 w values, 8 per thread
      int idx = (kk<<8) + t;
      int i = idx >> 6, j = idx & 63;
      float e = lrelu(sS[i] + dS[j]);
      unsigned int b = (bitS[i][j>>5] >> (j & 31)) & 1u;
      wt[i][j] = b ? __expf(e - mS[i]) : 0.f;
    }
    __syncthreads();
    { // per-row weight sums (16-lane-group shuffle reduce)
      float v0 = wt[rl][c]   + wt[rl][c+16]   + wt[rl][c+32]   + wt[rl][c+48];
      float v1 = wt[rl+1][c] + wt[rl+1][c+16] + wt[rl+1][c+32] + wt[rl+1][c+48];
      #pragma unroll
      for (int off = 1; off < 16; off <<= 1){ v0 += __shfl_xor(v0, off); v1 += __shfl_xor(v1, off); }
      sw0 += v0; sw1 += v1;
    }
    #pragma unroll 8
    for (int j = 0; j < 64; ++j){
      const float4 whv = *(const float4*)&WhS[j][cc<<2];
      const float w0 = wt[rl][j], w1 = wt[rl+1][j];
      a0.x=fmaf(w0,whv.x,a0.x); a0.y=fmaf(w0,whv.y,a0.y); a0.z=fmaf(w0,whv.z,a0.z); a0.w=fmaf(w0,whv.w,a0.w);
      a1.x=fmaf(w1,whv.x,a1.x); a1.y=fmaf(w1,whv.y,a1.y); a1.z=fmaf(w1,whv.z,a1.z); a1.w=fmaf(w1,whv.w,a1.w);
    }
  }
  const float n0 = 1.f/sw0, n1 = 1.f/sw1;
  float4 r0 = make_float4(a0.x*n0, a0.y*n0, a0.z*n0, a0.w*n0);
  float4 r1 = make_float4(a1.x*n1, a1.y*n1, a1.z*n1, a1.w*n1);
  if (DO_ELU){
    r0.x = r0.x>0.f?r0.x:__expf(r0.x)-1.f; r0.y = r0.y>0.f?r0.y:__expf(r0.y)-1.f;
    r0.z = r0.z>0.f?r0.z:__expf(r0.z)-1.f; r0.w = r0.w>0.f?r0.w:__expf(r0.w)-1.f;
    r1.x = r1.x>0.f?r1.x:__expf(r1.x)-1.f; r1.y = r1.y>0.f?r1.y:__expf(r1.y)-1.f;
    r1.z = r1.z>0.f?r1.z:__expf(r1.z)-1.f; r1.w = r1.w>0.f?r1.w:__expf(r1.w)-1.f;
  }
  if (c < NCG){
    *(float4*)&outp[(size_t)(i0+rl  )*OSTR + h*64 + (c<<2)] = r0;
    *(float4*)&outp[(size_t)(i0+rl+1)*OSTR + h*64 + (c<<2)] = r1;
  }
}

// ---------------- Wh2 = hbuf @ W_out ; s2/d2 = Wh2 @ ao_src/ao_dst ----------------
__global__ __launch_bounds__(256) void wh2_k(const float* __restrict__ hb, const float* __restrict__ Wout,
                                             const float* __restrict__ aos, const float* __restrict__ aod,
                                             float* __restrict__ Wh2, float* __restrict__ s2, float* __restrict__ d2){
  const int wv = threadIdx.x >> 6, c = threadIdx.x & 63;
  const int cw = c < NCLS ? c : NCLS-1;
  const int r0 = blockIdx.x*16 + (wv << 2);
  float acc[4] = {0,0,0,0};
  #pragma unroll 4
  for (int k = 0; k < 512; ++k){
    float w = Wout[k*NCLS + cw];
    #pragma unroll
    for (int r = 0; r < 4; ++r) acc[r] = fmaf(hb[(size_t)(r0+r)*512 + k], w, acc[r]);
  }
  float as = (c < NCLS) ? aos[c] : 0.f;
  float ad = (c < NCLS) ? aod[c] : 0.f;
  #pragma unroll
  for (int r = 0; r < 4; ++r){
    if (c < NCLS) Wh2[(size_t)(r0+r)*NCLS + c] = acc[r];
    float ps = acc[r]*as, pd = acc[r]*ad;
    #pragma unroll
    for (int off = 32; off; off >>= 1){ ps += __shfl_down(ps, off); pd += __shfl_down(pd, off); }
    if (c == 0){ s2[r0+r] = ps; d2[r0+r] = pd; }
  }
}

// ---------------- elu + row log_softmax (one wave per row) ----------------
__global__ __launch_bounds__(256) void final_k(const float* __restrict__ pre, float* __restrict__ out){
  const int wid = (blockIdx.x*256 + threadIdx.x) >> 6;
  const int c = threadIdx.x & 63;
  float xv = (c < NCLS) ? pre[(size_t)wid*NCLS + c] : 0.f;
  float e  = xv > 0.f ? xv : __expf(xv) - 1.f;
  float ev = (c < NCLS) ? e : -3.0e38f;
  float m = ev;
  #pragma unroll
  for (int off = 32; off; off >>= 1) m = fmaxf(m, __shfl_xor(m, off));
  float ex = (c < NCLS) ? __expf(e - m) : 0.f;
  float s = ex;
  #pragma unroll
  for (int off = 32; off; off >>= 1) s += __shfl_xor(s, off);
  if (c < NCLS) out[(size_t)wid*NCLS + c] = e - m - __logf(s);
}

extern "C" void kernel_launch(void* const* d_in, const int* in_sizes, int n_in,
                              void* d_out, int out_size, void* d_ws, size_t ws_size,
                              hipStream_t stream){
  (void)in_sizes; (void)n_in; (void)out_size; (void)ws_size;
  const float* x     = (const float*)d_in[0];
  const int*   adj   = (const int*)  d_in[1];
  const float* W     = (const float*)d_in[2];
  const float* a_src = (const float*)d_in[3];
  const float* a_dst = (const float*)d_in[4];
  const float* W_out = (const float*)d_in[5];
  const float* aos   = (const float*)d_in[6];
  const float* aod   = (const float*)d_in[7];
  float* out = (float*)d_out;

  float* p = (float*)d_ws;
  unsigned int* bm = (unsigned int*)p; p += (size_t)NN*NWRD;   // 2 MB
  float* Whc  = p; p += (size_t)NN*512;                        // 8 MB
  float* hbuf = p; p += (size_t)NN*512;                        // 8 MB
  float* srcv = p; p += (size_t)NHEAD*NN;
  float* dstv = p; p += (size_t)NHEAD*NN;
  float* maxd = p; p += (size_t)NHEAD*NN;
  float* Wh2  = p; p += (size_t)NN*NCLS;
  float* s2   = p; p += NN;
  float* d2   = p; p += NN;
  float* m2   = p; p += NN;
  float* pre  = p; p += (size_t)NN*NCLS;

  pack_adj_k<<<(NN*NN)/256, 256, 0, stream>>>(adj, bm);
  gemm_wh_k<<<dim3(NN/64, NHEAD), 256, 0, stream>>>(x, W, Whc);
  src_dst_k<<<NN, 512, 0, stream>>>(Whc, a_src, a_dst, srcv, dstv);
  row_max_k<<<(NHEAD*NN)/4, 256, 0, stream>>>(bm, dstv, maxd, NHEAD*NN);
  aggregate_k<64, 512, 512, true><<<dim3(NN/32, NHEAD), 256, 0, stream>>>(bm, Whc, srcv, dstv, maxd, hbuf);
  wh2_k<<<NN/16, 256, 0, stream>>>(hbuf, W_out, aos, aod, Wh2, s2, d2);
  row_max_k<<<NN/4, 256, 0, stream>>>(bm, d2, m2, NN);
  aggregate_k<40, 40, 40, false><<<dim3(NN/32, 1), 256, 0, stream>>>(bm, Wh2, s2, d2, m2, pre);
  final_k<<<NN/4, 256, 0, stream>>>(pre, out);
}

// Round 2
// 453.828 us; speedup vs baseline: 2.0933x; 2.0933x over previous
//
#include <hip/hip_runtime.h>

#define NN 4096
#define F_IN 1024
#define NHEAD 8
#define HID 64
#define NCLS 40
#define LRA 0.2f
#define NWRD 128   // 32-bit words per bitmask row

typedef float f32x4 __attribute__((ext_vector_type(4)));
typedef short s16x8 __attribute__((ext_vector_type(8)));

__device__ __forceinline__ float lrelu(float x){ return x > 0.f ? x : LRA*x; }
__device__ __forceinline__ unsigned short f2bf(float f){  // RNE float->bf16
  unsigned int u = __float_as_uint(f);
  return (unsigned short)((u + 0x7fffu + ((u >> 16) & 1u)) >> 16);
}

// ---------------- pack adjacency -> row-major bitmask + word-transposed bitmask ----------------
__global__ __launch_bounds__(256) void pack_adj_k(const int* __restrict__ adj,
                                                  unsigned* __restrict__ bm, unsigned* __restrict__ bmT){
  int gid = blockIdx.x*256 + threadIdx.x;
  int lane = threadIdx.x & 63;
  unsigned long long m = __ballot(adj[gid] > 0);
  int w = gid >> 5;              // word index = i*128 + jw
  int i = w >> 7, jw = w & 127;
  if (lane == 0)      { bm[w] = (unsigned)m;        bmT[(size_t)jw*NN + i] = (unsigned)m; }
  else if (lane == 32){ bm[w] = (unsigned)(m >> 32); bmT[(size_t)jw*NN + i] = (unsigned)(m >> 32); }
}

// ---------------- WbT[h][o][k] = bf16(W[h][k][o]) ----------------
__global__ __launch_bounds__(256) void cast_W_k(const float* __restrict__ W, unsigned short* __restrict__ WbT){
  __shared__ float T[64][65];
  const int h = blockIdx.y, k0 = blockIdx.x*64, t = threadIdx.x;
  for (int idx = t; idx < 1024; idx += 256){
    int k = idx >> 4, c4 = idx & 15;
    *(float4*)&T[k][c4*4] = *(const float4*)&W[((size_t)h*F_IN + k0 + k)*HID + c4*4];
  }
  __syncthreads();
  for (int idx = t; idx < 512; idx += 256){
    int o = idx >> 3, ch = idx & 7;
    s16x8 v;
    #pragma unroll
    for (int e = 0; e < 8; ++e) v[e] = (short)f2bf(T[ch*8 + e][o]);
    *(s16x8*)&WbT[((size_t)h*HID + o)*F_IN + k0 + ch*8] = v;
  }
}

// ---------------- Whc[n][h*64+o] (fp32) and WhT[h][o][n] (bf16) = x @ W via MFMA ----------------
__global__ __launch_bounds__(256) void gemm_wh_mfma_k(const float* __restrict__ x,
    const unsigned short* __restrict__ WbT, float* __restrict__ Whc, unsigned short* __restrict__ WhT){
  __shared__ unsigned short xS[64][72];
  __shared__ unsigned short wS[64][72];
  const int t = threadIdx.x, l = t & 63, wv = t >> 6, g = l >> 4, c = l & 15;
  const int h = blockIdx.y, n0 = blockIdx.x * 64;
  f32x4 acc[4] = {};
  for (int k0 = 0; k0 < F_IN; k0 += 64){
    __syncthreads();
    #pragma unroll
    for (int p = 0; p < 4; ++p){          // stage x tile, fp32 -> bf16
      int idx = t + p*256;
      int row = idx >> 4, c4 = idx & 15;
      float4 v = *(const float4*)&x[(size_t)(n0+row)*F_IN + k0 + c4*4];
      unsigned p0 = (unsigned)f2bf(v.x) | ((unsigned)f2bf(v.y) << 16);
      unsigned p1 = (unsigned)f2bf(v.z) | ((unsigned)f2bf(v.w) << 16);
      *(uint2*)&xS[row][c4*4] = make_uint2(p0, p1);
    }
    #pragma unroll
    for (int p = 0; p < 2; ++p){          // stage W^T tile (already bf16)
      int idx = t + p*256;
      int o = idx >> 3, ch = idx & 7;
      *(s16x8*)&wS[o][ch*8] = *(const s16x8*)&WbT[(size_t)(h*HID + o)*F_IN + k0 + ch*8];
    }
    __syncthreads();
    #pragma unroll
    for (int ks = 0; ks < 2; ++ks){
      s16x8 av = *(const s16x8*)&xS[wv*16 + c][ks*32 + g*8];
      #pragma unroll
      for (int ct = 0; ct < 4; ++ct){
        s16x8 bv = *(const s16x8*)&wS[ct*16 + c][ks*32 + g*8];
        acc[ct] = __builtin_amdgcn_mfma_f32_16x16x32_bf16(av, bv, acc[ct], 0, 0, 0);
      }
    }
  }
  #pragma unroll
  for (int ct = 0; ct < 4; ++ct)
    #pragma unroll
    for (int r = 0; r < 4; ++r)
      Whc[(size_t)(n0 + wv*16 + g*4 + r)*(NHEAD*HID) + h*HID + ct*16 + c] = acc[ct][r];
  // transposed bf16 tile via LDS bounce (reuse xS)
  __syncthreads();
  #pragma unroll
  for (int ct = 0; ct < 4; ++ct){
    unsigned p0 = (unsigned)f2bf(acc[ct][0]) | ((unsigned)f2bf(acc[ct][1]) << 16);
    unsigned p1 = (unsigned)f2bf(acc[ct][2]) | ((unsigned)f2bf(acc[ct][3]) << 16);
    *(uint2*)&xS[ct*16 + c][wv*16 + g*4] = make_uint2(p0, p1);
  }
  __syncthreads();
  #pragma unroll
  for (int p = 0; p < 2; ++p){
    int idx = t + p*256;
    int o = idx >> 3, ch = idx & 7;
    *(s16x8*)&WhT[(size_t)(h*HID + o)*NN + n0 + ch*8] = *(const s16x8*)&xS[o][ch*8];
  }
}

// ---------------- src[h][n], dst[h][n] ----------------
__global__ __launch_bounds__(512) void src_dst_k(const float* __restrict__ Whc,
                                                 const float* __restrict__ a_src, const float* __restrict__ a_dst,
                                                 float* __restrict__ srcv, float* __restrict__ dstv){
  const int n = blockIdx.x;
  const int h = threadIdx.x >> 6, o = threadIdx.x & 63;
  float v  = Whc[(size_t)n*(NHEAD*HID) + h*HID + o];
  float ps = v * a_src[h*HID + o];
  float pd = v * a_dst[h*HID + o];
  #pragma unroll
  for (int off = 32; off; off >>= 1){ ps += __shfl_down(ps, off); pd += __shfl_down(pd, off); }
  if (o == 0){ srcv[h*NN + n] = ps; dstv[h*NN + n] = pd; }
}

// ---------------- maxd[i] = max over neighbors j of dst[j] (one wave per row) ----------------
__global__ __launch_bounds__(256) void row_max_k(const unsigned* __restrict__ bm,
                                                 const float* __restrict__ dstv, float* __restrict__ maxd,
                                                 int total){
  const int wid = (blockIdx.x*256 + threadIdx.x) >> 6;
  if (wid >= total) return;
  const int lane = threadIdx.x & 63;
  const int i = wid & (NN - 1);
  const float* dh = dstv + (size_t)(wid >> 12)*NN;
  const unsigned* row = bm + (size_t)i*NWRD;
  float m = -3.0e38f;
  for (int j0 = 0; j0 < NN; j0 += 64){
    unsigned w = row[(j0 >> 5) + (lane >> 5)];
    if ((w >> (lane & 31)) & 1u) m = fmaxf(m, dh[j0 + lane]);
  }
  #pragma unroll
  for (int off = 32; off; off >>= 1) m = fmaxf(m, __shfl_xor(m, off));
  if (lane == 0) maxd[wid] = m;
}

// ---------------- MFMA masked-softmax aggregate ----------------
// Block: 64 rows x NCT*16 cols, one head. 4 waves x 16 rows. P built in-register (A frag),
// V from pre-transposed bf16 VT[o][n] staged in padded LDS (B frag via ds_read_b128).
template<int NCT, int OSTR, bool DO_ELU>
__global__ __launch_bounds__(256) void agg_mfma_k(const unsigned* __restrict__ bmT,
    const unsigned short* __restrict__ VT, const float* __restrict__ srcv,
    const float* __restrict__ dstv, const float* __restrict__ maxd, float* __restrict__ outp){
  __shared__ unsigned short vS[NCT*16][72];
  __shared__ float dS[64];
  __shared__ unsigned bitS[2][64];
  const int t = threadIdx.x, l = t & 63, wv = t >> 6, g = l >> 4, c = l & 15;
  const int h = blockIdx.y, i0 = blockIdx.x * 64;
  const int lr = wv*16 + c;                        // A-fragment row (local)
  const float sr = srcv[h*NN + i0 + lr];
  const float mi = lrelu(sr + maxd[h*NN + i0 + lr]);
  const unsigned short* vb = VT + (size_t)h*HID*NN;
  f32x4 acc[NCT] = {};
  float rs = 0.f;
  for (int jt = 0; jt < NN/64; ++jt){
    __syncthreads();
    for (int idx = t; idx < NCT*128; idx += 256){
      int o = idx >> 3, ch = idx & 7;
      *(s16x8*)&vS[o][ch*8] = *(const s16x8*)&vb[(size_t)o*NN + jt*64 + ch*8];
    }
    if (t < 64) dS[t] = dstv[h*NN + jt*64 + t];
    else if (t < 192) bitS[(t-64)>>6][t&63] = bmT[(size_t)(jt*2 + ((t-64)>>6))*NN + i0 + (t & 63)];
    __syncthreads();
    #pragma unroll
    for (int ks = 0; ks < 2; ++ks){
      unsigned wbits = (bitS[ks][lr] >> (g*8)) & 0xffu;
      const float4 d0 = *(const float4*)&dS[ks*32 + g*8];
      const float4 d1 = *(const float4*)&dS[ks*32 + g*8 + 4];
      float pj[8];
      pj[0] = (wbits & 1u)   ? __expf(lrelu(sr + d0.x) - mi) : 0.f;
      pj[1] = (wbits & 2u)   ? __expf(lrelu(sr + d0.y) - mi) : 0.f;
      pj[2] = (wbits & 4u)   ? __expf(lrelu(sr + d0.z) - mi) : 0.f;
      pj[3] = (wbits & 8u)   ? __expf(lrelu(sr + d0.w) - mi) : 0.f;
      pj[4] = (wbits & 16u)  ? __expf(lrelu(sr + d1.x) - mi) : 0.f;
      pj[5] = (wbits & 32u)  ? __expf(lrelu(sr + d1.y) - mi) : 0.f;
      pj[6] = (wbits & 64u)  ? __expf(lrelu(sr + d1.z) - mi) : 0.f;
      pj[7] = (wbits & 128u) ? __expf(lrelu(sr + d1.w) - mi) : 0.f;
      rs += ((pj[0]+pj[1])+(pj[2]+pj[3])) + ((pj[4]+pj[5])+(pj[6]+pj[7]));
      s16x8 af;
      #pragma unroll
      for (int e = 0; e < 8; ++e) af[e] = (short)f2bf(pj[e]);
      #pragma unroll
      for (int ct = 0; ct < NCT; ++ct){
        s16x8 bv = *(const s16x8*)&vS[ct*16 + c][ks*32 + g*8];
        acc[ct] = __builtin_amdgcn_mfma_f32_16x16x32_bf16(af, bv, acc[ct], 0, 0, 0);
      }
    }
  }
  // row sums: reduce over k-groups, then redistribute to C/D rows 4g+r
  rs += __shfl_xor(rs, 16);
  rs += __shfl_xor(rs, 32);
  float inv[4];
  #pragma unroll
  for (int r = 0; r < 4; ++r) inv[r] = 1.f / __shfl(rs, g*4 + r);
  #pragma unroll
  for (int ct = 0; ct < NCT; ++ct){
    int col = ct*16 + c;
    if (NCT == 3 && col >= NCLS) continue;
    #pragma unroll
    for (int r = 0; r < 4; ++r){
      float v = acc[ct][r] * inv[r];
      if (DO_ELU) v = v > 0.f ? v : __expf(v) - 1.f;
      outp[(size_t)(i0 + wv*16 + g*4 + r)*OSTR + (OSTR == NHEAD*HID ? h*HID : 0) + col] = v;
    }
  }
}

// ---------------- Wh2 = hbuf @ W_out ; s2/d2 = Wh2 @ ao_src/ao_dst ----------------
__global__ __launch_bounds__(256) void wh2_k(const float* __restrict__ hb, const float* __restrict__ Wout,
                                             const float* __restrict__ aos, const float* __restrict__ aod,
                                             float* __restrict__ Wh2, float* __restrict__ s2, float* __restrict__ d2){
  const int wv = threadIdx.x >> 6, c = threadIdx.x & 63;
  const int cw = c < NCLS ? c : NCLS-1;
  const int r0 = blockIdx.x*16 + (wv << 2);
  float acc[4] = {0,0,0,0};
  #pragma unroll 4
  for (int k = 0; k < NHEAD*HID; ++k){
    float w = Wout[k*NCLS + cw];
    #pragma unroll
    for (int r = 0; r < 4; ++r) acc[r] = fmaf(hb[(size_t)(r0+r)*(NHEAD*HID) + k], w, acc[r]);
  }
  float as = (c < NCLS) ? aos[c] : 0.f;
  float ad = (c < NCLS) ? aod[c] : 0.f;
  #pragma unroll
  for (int r = 0; r < 4; ++r){
    if (c < NCLS) Wh2[(size_t)(r0+r)*NCLS + c] = acc[r];
    float ps = acc[r]*as, pd = acc[r]*ad;
    #pragma unroll
    for (int off = 32; off; off >>= 1){ ps += __shfl_down(ps, off); pd += __shfl_down(pd, off); }
    if (c == 0){ s2[r0+r] = ps; d2[r0+r] = pd; }
  }
}

// ---------------- WhT2[c][j] = bf16(Wh2[j][c]), rows 40..47 zero ----------------
__global__ __launch_bounds__(256) void t2_k(const float* __restrict__ Wh2, unsigned short* __restrict__ WhT2){
  __shared__ float T[64][49];
  const int j0 = blockIdx.x*64, t = threadIdx.x;
  for (int idx = t; idx < 64*48; idx += 256){
    int j = idx / 48, c = idx - j*48;
    T[j][c] = (c < NCLS) ? Wh2[(size_t)(j0 + j)*NCLS + c] : 0.f;
  }
  __syncthreads();
  for (int idx = t; idx < 48*8; idx += 256){
    int o = idx >> 3, ch = idx & 7;
    s16x8 v;
    #pragma unroll
    for (int e = 0; e < 8; ++e) v[e] = (short)f2bf(T[ch*8 + e][o]);
    *(s16x8*)&WhT2[(size_t)o*NN + j0 + ch*8] = v;
  }
}

// ---------------- elu + row log_softmax ----------------
__global__ __launch_bounds__(256) void final_k(const float* __restrict__ pre, float* __restrict__ out){
  const int wid = (blockIdx.x*256 + threadIdx.x) >> 6;
  const int c = threadIdx.x & 63;
  float xv = (c < NCLS) ? pre[(size_t)wid*NCLS + c] : 0.f;
  float e  = xv > 0.f ? xv : __expf(xv) - 1.f;
  float ev = (c < NCLS) ? e : -3.0e38f;
  float m = ev;
  #pragma unroll
  for (int off = 32; off; off >>= 1) m = fmaxf(m, __shfl_xor(m, off));
  float ex = (c < NCLS) ? __expf(e - m) : 0.f;
  float s = ex;
  #pragma unroll
  for (int off = 32; off; off >>= 1) s += __shfl_xor(s, off);
  if (c < NCLS) out[(size_t)wid*NCLS + c] = e - m - __logf(s);
}

extern "C" void kernel_launch(void* const* d_in, const int* in_sizes, int n_in,
                              void* d_out, int out_size, void* d_ws, size_t ws_size,
                              hipStream_t stream){
  (void)in_sizes; (void)n_in; (void)out_size; (void)ws_size;
  const float* x     = (const float*)d_in[0];
  const int*   adj   = (const int*)  d_in[1];
  const float* W     = (const float*)d_in[2];
  const float* a_src = (const float*)d_in[3];
  const float* a_dst = (const float*)d_in[4];
  const float* W_out = (const float*)d_in[5];
  const float* aos   = (const float*)d_in[6];
  const float* aod   = (const float*)d_in[7];
  float* out = (float*)d_out;

  char* p = (char*)d_ws;
  unsigned* bm   = (unsigned*)p;        p += (size_t)NN*NWRD*4;        // 2 MB
  unsigned* bmT  = (unsigned*)p;        p += (size_t)NN*NWRD*4;        // 2 MB
  float* Whc     = (float*)p;           p += (size_t)NN*NHEAD*HID*4;   // 8 MB
  float* hbuf    = (float*)p;           p += (size_t)NN*NHEAD*HID*4;   // 8 MB
  float* Wh2     = (float*)p;           p += (size_t)NN*NCLS*4;
  float* pre     = (float*)p;           p += (size_t)NN*NCLS*4;
  float* srcv    = (float*)p;           p += (size_t)NHEAD*NN*4;
  float* dstv    = (float*)p;           p += (size_t)NHEAD*NN*4;
  float* maxd    = (float*)p;           p += (size_t)NHEAD*NN*4;
  float* s2      = (float*)p;           p += (size_t)NN*4;
  float* d2      = (float*)p;           p += (size_t)NN*4;
  float* m2      = (float*)p;           p += (size_t)NN*4;
  unsigned short* WbT  = (unsigned short*)p; p += (size_t)NHEAD*HID*F_IN*2;  // 1 MB
  unsigned short* WhT  = (unsigned short*)p; p += (size_t)NHEAD*HID*NN*2;    // 4 MB
  unsigned short* WhT2 = (unsigned short*)p; p += (size_t)48*NN*2;           // 384 KB

  pack_adj_k<<<(NN*NN)/256, 256, 0, stream>>>(adj, bm, bmT);
  cast_W_k<<<dim3(F_IN/64, NHEAD), 256, 0, stream>>>(W, WbT);
  gemm_wh_mfma_k<<<dim3(NN/64, NHEAD), 256, 0, stream>>>(x, WbT, Whc, WhT);
  src_dst_k<<<NN, 512, 0, stream>>>(Whc, a_src, a_dst, srcv, dstv);
  row_max_k<<<(NHEAD*NN)/4, 256, 0, stream>>>(bm, dstv, maxd, NHEAD*NN);
  agg_mfma_k<4, NHEAD*HID, true><<<dim3(NN/64, NHEAD), 256, 0, stream>>>(bmT, WhT, srcv, dstv, maxd, hbuf);
  wh2_k<<<NN/16, 256, 0, stream>>>(hbuf, W_out, aos, aod, Wh2, s2, d2);
  row_max_k<<<NN/4, 256, 0, stream>>>(bm, d2, m2, NN);
  t2_k<<<NN/64, 256, 0, stream>>>(Wh2, WhT2);
  agg_mfma_k<3, NCLS, false><<<dim3(NN/64, 1), 256, 0, stream>>>(bmT, WhT2, s2, d2, m2, pre);
  final_k<<<NN/4, 256, 0, stream>>>(pre, out);
}

// Round 3
// 174.448 us; speedup vs baseline: 5.4456x; 2.6015x over previous
//
#include <hip/hip_runtime.h>

#define NN 4096
#define F_IN 1024
#define NHEAD 8
#define HID 64
#define NCLS 40
#define LOG2E 1.44269504f

typedef float f32x4 __attribute__((ext_vector_type(4)));
typedef short s16x8 __attribute__((ext_vector_type(8)));

__device__ __forceinline__ unsigned short f2bf(float f){  // RNE float->bf16
  unsigned u = __float_as_uint(f);
  return (unsigned short)((u + 0x7fffu + ((u >> 16) & 1u)) >> 16);
}
__device__ __forceinline__ unsigned cvtpk(float lo, float hi){  // packed bf16 pair
  unsigned r; asm("v_cvt_pk_bf16_f32 %0, %1, %2" : "=v"(r) : "v"(lo), "v"(hi)); return r;
}

// ---------------- pack adjacency -> word-transposed bitmask ----------------
__global__ __launch_bounds__(256) void pack_adj_k(const int* __restrict__ adj, unsigned* __restrict__ bmT){
  int gid = blockIdx.x*256 + threadIdx.x;
  int lane = threadIdx.x & 63;
  unsigned long long m = __ballot(adj[gid] > 0);
  int w = gid >> 5, i = w >> 7, jw = w & 127;
  if (lane == 0)       bmT[(size_t)jw*NN + i] = (unsigned)m;
  else if (lane == 32) bmT[(size_t)jw*NN + i] = (unsigned)(m >> 32);
}

// ---------------- WbT[h][o][k] = bf16(W[h][k][o]) ----------------
__global__ __launch_bounds__(256) void cast_W_k(const float* __restrict__ W, unsigned short* __restrict__ WbT){
  __shared__ float T[64][65];
  const int h = blockIdx.y, k0 = blockIdx.x*64, t = threadIdx.x;
  for (int idx = t; idx < 1024; idx += 256){
    int k = idx >> 4, c4 = idx & 15;
    *(float4*)&T[k][c4*4] = *(const float4*)&W[((size_t)h*F_IN + k0 + k)*HID + c4*4];
  }
  __syncthreads();
  for (int idx = t; idx < 512; idx += 256){
    int o = idx >> 3, ch = idx & 7;
    s16x8 v;
    #pragma unroll
    for (int e = 0; e < 8; ++e) v[e] = (short)f2bf(T[ch*8 + e][o]);
    *(s16x8*)&WbT[((size_t)h*HID + o)*F_IN + k0 + ch*8] = v;
  }
}

// ---------------- WoT[c][k] = bf16(W_out[k][c]), rows 40..47 zero ----------------
__global__ __launch_bounds__(256) void cast_Wo_k(const float* __restrict__ Wout, unsigned short* __restrict__ WoT){
  int idx = blockIdx.x*256 + threadIdx.x;   // 48*512
  int cc = idx >> 9, k = idx & 511;
  WoT[idx] = (cc < NCLS) ? f2bf(Wout[(size_t)k*NCLS + cc]) : (unsigned short)0;
}

// ---------------- gemm1: WhT[h][o][n] bf16 = (x@W)^T ; srcv/dstv fused epilogue ----------------
__global__ __launch_bounds__(256) void gemm1_k(const float* __restrict__ x,
    const unsigned short* __restrict__ WbT, unsigned short* __restrict__ WhT,
    const float* __restrict__ a_src, const float* __restrict__ a_dst,
    float* __restrict__ srcv, float* __restrict__ dstv){
  __shared__ unsigned short xS[64][72];
  __shared__ unsigned short wS[64][72];
  const int t = threadIdx.x, l = t & 63, wv = t >> 6, g = l >> 4, c = l & 15;
  const int h = blockIdx.y, n0 = blockIdx.x * 64;
  f32x4 acc[4] = {};
  for (int k0 = 0; k0 < F_IN; k0 += 64){
    __syncthreads();
    #pragma unroll
    for (int p = 0; p < 4; ++p){
      int idx = t + p*256, row = idx >> 4, c4 = idx & 15;
      float4 v = *(const float4*)&x[(size_t)(n0+row)*F_IN + k0 + c4*4];
      *(uint2*)&xS[row][c4*4] = make_uint2(cvtpk(v.x, v.y), cvtpk(v.z, v.w));
    }
    #pragma unroll
    for (int p = 0; p < 2; ++p){
      int idx = t + p*256, o = idx >> 3, ch = idx & 7;
      *(s16x8*)&wS[o][ch*8] = *(const s16x8*)&WbT[(size_t)(h*HID + o)*F_IN + k0 + ch*8];
    }
    __syncthreads();
    #pragma unroll
    for (int ks = 0; ks < 2; ++ks){
      s16x8 av = *(const s16x8*)&xS[wv*16 + c][ks*32 + g*8];
      #pragma unroll
      for (int ct = 0; ct < 4; ++ct){
        s16x8 bv = *(const s16x8*)&wS[ct*16 + c][ks*32 + g*8];
        acc[ct] = __builtin_amdgcn_mfma_f32_16x16x32_bf16(av, bv, acc[ct], 0, 0, 0);
      }
    }
  }
  // fused src/dst: per-row dot with a_src/a_dst, 16-lane reduce
  float asv[4], adv[4];
  #pragma unroll
  for (int ct = 0; ct < 4; ++ct){ asv[ct] = a_src[h*HID + ct*16 + c]; adv[ct] = a_dst[h*HID + ct*16 + c]; }
  #pragma unroll
  for (int r = 0; r < 4; ++r){
    float ps = acc[0][r]*asv[0] + acc[1][r]*asv[1] + acc[2][r]*asv[2] + acc[3][r]*asv[3];
    float pd = acc[0][r]*adv[0] + acc[1][r]*adv[1] + acc[2][r]*adv[2] + acc[3][r]*adv[3];
    #pragma unroll
    for (int off = 1; off < 16; off <<= 1){ ps += __shfl_xor(ps, off); pd += __shfl_xor(pd, off); }
    if (c == 0){ int n = n0 + wv*16 + g*4 + r; srcv[h*NN + n] = ps; dstv[h*NN + n] = pd; }
  }
  // transposed bf16 out via LDS bounce
  __syncthreads();
  #pragma unroll
  for (int ct = 0; ct < 4; ++ct)
    *(uint2*)&xS[ct*16 + c][wv*16 + g*4] = make_uint2(cvtpk(acc[ct][0], acc[ct][1]), cvtpk(acc[ct][2], acc[ct][3]));
  __syncthreads();
  #pragma unroll
  for (int p = 0; p < 2; ++p){
    int idx = t + p*256, o = idx >> 3, ch = idx & 7;
    *(s16x8*)&WhT[(size_t)(h*HID + o)*NN + n0 + ch*8] = *(const s16x8*)&xS[o][ch*8];
  }
}

// ---------------- per-4096-segment max reduce ----------------
__global__ __launch_bounds__(256) void maxred_k(const float* __restrict__ in, float* __restrict__ out){
  __shared__ float red[4];
  const float* p = in + (size_t)blockIdx.x*NN;
  float m = -3.0e38f;
  for (int i = threadIdx.x; i < NN; i += 256) m = fmaxf(m, p[i]);
  #pragma unroll
  for (int off = 32; off; off >>= 1) m = fmaxf(m, __shfl_xor(m, off));
  if ((threadIdx.x & 63) == 0) red[threadIdx.x >> 6] = m;
  __syncthreads();
  if (threadIdx.x == 0) out[blockIdx.x] = fmaxf(fmaxf(red[0], red[1]), fmaxf(red[2], red[3]));
}

// ---------------- MFMA masked-softmax aggregate, 32 rows/block, wave j-split ----------------
// 4 waves: (wv&1)=row half (16 rows), (wv>>1)=j-tile parity. Row sums via ones-column MFMA.
template<int NCT, int NJT, bool CHUNKED, bool DO_ELU>
__global__ __launch_bounds__(256) void agg_mfma_k(
    const unsigned* __restrict__ bmT, const unsigned short* __restrict__ VT,
    const float* __restrict__ srcv, const float* __restrict__ dstv,
    const float* __restrict__ maxp, void* __restrict__ outp)
{
  __shared__ unsigned short vS[2][NCT*16][72];
  __shared__ float dS[2][64];
  __shared__ unsigned bitS[2][2][32];
  const int t = threadIdx.x, l = t & 63, wv = t >> 6, g = l >> 4, c = l & 15;
  const int h   = CHUNKED ? 0 : blockIdx.y;
  const int jt0 = CHUNKED ? blockIdx.y * NJT : 0;
  const int i0 = blockIdx.x * 32;
  const int tl = wv >> 1, rH = wv & 1;
  const int lr = rH*16 + c;
  const float sr = srcv[h*NN + i0 + lr];
  const float mx = maxp[CHUNKED ? 0 : h];
  const float tm = sr + mx;
  const float mi2 = fmaxf(tm, 0.2f*tm) * LOG2E;
  const unsigned short* vb = VT + (CHUNKED ? (size_t)0 : (size_t)h*HID*NN);

  f32x4 acc[NCT] = {};
  f32x4 accs = {};
  s16x8 ones;
  #pragma unroll
  for (int e = 0; e < 8; ++e) ones[e] = (short)0x3F80;

  s16x8 vreg[NCT]; float dreg = 0.f; unsigned breg = 0;
  auto loadRegs = [&](int jt){
    #pragma unroll
    for (int p = 0; p < NCT; ++p){
      int u = t + p*256;
      int tt = u / (NCT*128), rem = u % (NCT*128);
      int o = rem >> 3, ch = rem & 7;
      vreg[p] = *(const s16x8*)&vb[(size_t)o*NN + (jt+tt)*64 + ch*8];
    }
    if (t < 128) dreg = dstv[h*NN + (jt + (t>>6))*64 + (t&63)];
    else { int u = t - 128; breg = bmT[(size_t)((jt + (u>>6))*2 + ((u>>5)&1))*NN + i0 + (u&31)]; }
  };
  auto writeLDS = [&](){
    #pragma unroll
    for (int p = 0; p < NCT; ++p){
      int u = t + p*256;
      int tt = u / (NCT*128), rem = u % (NCT*128);
      int o = rem >> 3, ch = rem & 7;
      *(s16x8*)&vS[tt][o][ch*8] = vreg[p];
    }
    if (t < 128) dS[t>>6][t&63] = dreg;
    else { int u = t - 128; bitS[u>>6][(u>>5)&1][u&31] = breg; }
  };

  loadRegs(jt0);
  for (int jj = 0; jj < NJT; jj += 2){
    __syncthreads();
    writeLDS();
    __syncthreads();
    if (jj + 2 < NJT) loadRegs(jt0 + jj + 2);
    #pragma unroll
    for (int ks = 0; ks < 2; ++ks){
      unsigned wb = (bitS[tl][ks][lr] >> (g*8)) & 0xffu;
      float4 dA = *(const float4*)&dS[tl][ks*32 + g*8];
      float4 dB = *(const float4*)&dS[tl][ks*32 + g*8 + 4];
      float q[8];
      float dv[8] = {dA.x, dA.y, dA.z, dA.w, dB.x, dB.y, dB.z, dB.w};
      #pragma unroll
      for (int e = 0; e < 8; ++e){
        float t1 = sr + dv[e];
        float lv = fmaxf(t1, 0.2f*t1);
        float a = fmaf(lv, LOG2E, -mi2);
        a = (wb & (1u << e)) ? a : -100.f;
        q[e] = exp2f(a);
      }
      s16x8 af;
      ((unsigned*)&af)[0] = cvtpk(q[0], q[1]);
      ((unsigned*)&af)[1] = cvtpk(q[2], q[3]);
      ((unsigned*)&af)[2] = cvtpk(q[4], q[5]);
      ((unsigned*)&af)[3] = cvtpk(q[6], q[7]);
      #pragma unroll
      for (int ct = 0; ct < NCT; ++ct){
        s16x8 bv = *(const s16x8*)&vS[tl][ct*16 + c][ks*32 + g*8];
        acc[ct] = __builtin_amdgcn_mfma_f32_16x16x32_bf16(af, bv, acc[ct], 0, 0, 0);
      }
      accs = __builtin_amdgcn_mfma_f32_16x16x32_bf16(af, ones, accs, 0, 0, 0);
    }
  }
  // merge j-split wave pairs via LDS
  __syncthreads();
  float* mrg = (float*)&vS[0][0][0];
  constexpr int S = (NCT + 1) * 4;
  if (tl == 1){
    int base = (rH*64 + l) * S;
    #pragma unroll
    for (int ct = 0; ct < NCT; ++ct)
      #pragma unroll
      for (int r = 0; r < 4; ++r) mrg[base + ct*4 + r] = acc[ct][r];
    #pragma unroll
    for (int r = 0; r < 4; ++r) mrg[base + NCT*4 + r] = accs[r];
  }
  __syncthreads();
  if (tl == 0){
    int base = (rH*64 + l) * S;
    #pragma unroll
    for (int ct = 0; ct < NCT; ++ct)
      #pragma unroll
      for (int r = 0; r < 4; ++r) acc[ct][r] += mrg[base + ct*4 + r];
    #pragma unroll
    for (int r = 0; r < 4; ++r) accs[r] += mrg[base + NCT*4 + r];
    if (!CHUNKED){
      unsigned short* ob = (unsigned short*)outp;
      #pragma unroll
      for (int r = 0; r < 4; ++r){
        float inv = 1.f / accs[r];
        int row = i0 + rH*16 + g*4 + r;
        #pragma unroll
        for (int ct = 0; ct < NCT; ++ct){
          float v = acc[ct][r] * inv;
          if (DO_ELU) v = v > 0.f ? v : __expf(v) - 1.f;
          ob[(size_t)row*(NHEAD*HID) + h*HID + ct*16 + c] = f2bf(v);
        }
      }
    } else {
      float* ob = (float*)outp + (size_t)blockIdx.y * NN * 64;
      #pragma unroll
      for (int r = 0; r < 4; ++r){
        int row = i0 + rH*16 + g*4 + r;
        #pragma unroll
        for (int ct = 0; ct < NCT; ++ct)
          ob[(size_t)row*64 + ct*16 + c] = acc[ct][r];
        if (c == 0) ob[(size_t)row*64 + 48] = accs[r];
      }
    }
  }
}

// ---------------- gemm2: WhT2[c][n] bf16 = (h_bf16 @ W_out)^T ; s2/d2 fused ----------------
__global__ __launch_bounds__(256) void gemm2_k(const unsigned short* __restrict__ hb,
    const unsigned short* __restrict__ WoT, const float* __restrict__ aos, const float* __restrict__ aod,
    unsigned short* __restrict__ WhT2, float* __restrict__ s2, float* __restrict__ d2){
  __shared__ unsigned short aS[64][72];
  __shared__ unsigned short bS[48][72];
  const int t = threadIdx.x, l = t & 63, wv = t >> 6, g = l >> 4, c = l & 15;
  const int n0 = blockIdx.x * 64;
  f32x4 acc[3] = {};
  for (int k0 = 0; k0 < NHEAD*HID; k0 += 64){
    __syncthreads();
    #pragma unroll
    for (int p = 0; p < 2; ++p){
      int u = t + p*256, o = u >> 3, ch = u & 7;
      *(s16x8*)&aS[o][ch*8] = *(const s16x8*)&hb[(size_t)(n0+o)*(NHEAD*HID) + k0 + ch*8];
    }
    for (int u = t; u < 384; u += 256){
      int o = u >> 3, ch = u & 7;
      *(s16x8*)&bS[o][ch*8] = *(const s16x8*)&WoT[(size_t)o*(NHEAD*HID) + k0 + ch*8];
    }
    __syncthreads();
    #pragma unroll
    for (int ks = 0; ks < 2; ++ks){
      s16x8 av = *(const s16x8*)&aS[wv*16 + c][ks*32 + g*8];
      #pragma unroll
      for (int ct = 0; ct < 3; ++ct){
        s16x8 bv = *(const s16x8*)&bS[ct*16 + c][ks*32 + g*8];
        acc[ct] = __builtin_amdgcn_mfma_f32_16x16x32_bf16(av, bv, acc[ct], 0, 0, 0);
      }
    }
  }
  float asv[3], adv[3];
  #pragma unroll
  for (int ct = 0; ct < 3; ++ct){
    int col = ct*16 + c;
    asv[ct] = (col < NCLS) ? aos[col] : 0.f;
    adv[ct] = (col < NCLS) ? aod[col] : 0.f;
  }
  #pragma unroll
  for (int r = 0; r < 4; ++r){
    float ps = acc[0][r]*asv[0] + acc[1][r]*asv[1] + acc[2][r]*asv[2];
    float pd = acc[0][r]*adv[0] + acc[1][r]*adv[1] + acc[2][r]*adv[2];
    #pragma unroll
    for (int off = 1; off < 16; off <<= 1){ ps += __shfl_xor(ps, off); pd += __shfl_xor(pd, off); }
    if (c == 0){ int n = n0 + wv*16 + g*4 + r; s2[n] = ps; d2[n] = pd; }
  }
  __syncthreads();
  #pragma unroll
  for (int ct = 0; ct < 3; ++ct)
    *(uint2*)&bS[ct*16 + c][wv*16 + g*4] = make_uint2(cvtpk(acc[ct][0], acc[ct][1]), cvtpk(acc[ct][2], acc[ct][3]));
  __syncthreads();
  for (int u = t; u < 384; u += 256){
    int o = u >> 3, ch = u & 7;
    *(s16x8*)&WhT2[(size_t)o*NN + n0 + ch*8] = *(const s16x8*)&bS[o][ch*8];
  }
}

// ---------------- merge 8 chunks + elu + row log_softmax ----------------
__global__ __launch_bounds__(256) void final_k(const float* __restrict__ part, float* __restrict__ out){
  const int wid = (blockIdx.x*256 + threadIdx.x) >> 6;
  const int c = threadIdx.x & 63;
  float acc = 0.f, rs = 0.f;
  #pragma unroll
  for (int ch = 0; ch < 8; ++ch){
    const float* pb = part + ((size_t)ch*NN + wid)*64;
    if (c < 48) acc += pb[c];
    rs += pb[48];
  }
  float v = acc / rs;
  float e = v > 0.f ? v : __expf(v) - 1.f;
  float ev = (c < NCLS) ? e : -3.0e38f;
  float m = ev;
  #pragma unroll
  for (int off = 32; off; off >>= 1) m = fmaxf(m, __shfl_xor(m, off));
  float ex = (c < NCLS) ? __expf(e - m) : 0.f;
  float s = ex;
  #pragma unroll
  for (int off = 32; off; off >>= 1) s += __shfl_xor(s, off);
  if (c < NCLS) out[(size_t)wid*NCLS + c] = e - m - __logf(s);
}

extern "C" void kernel_launch(void* const* d_in, const int* in_sizes, int n_in,
                              void* d_out, int out_size, void* d_ws, size_t ws_size,
                              hipStream_t stream){
  (void)in_sizes; (void)n_in; (void)out_size; (void)ws_size;
  const float* x     = (const float*)d_in[0];
  const int*   adj   = (const int*)  d_in[1];
  const float* W     = (const float*)d_in[2];
  const float* a_src = (const float*)d_in[3];
  const float* a_dst = (const float*)d_in[4];
  const float* W_out = (const float*)d_in[5];
  const float* aos   = (const float*)d_in[6];
  const float* aod   = (const float*)d_in[7];
  float* out = (float*)d_out;

  char* p = (char*)d_ws;
  unsigned* bmT        = (unsigned*)p;       p += (size_t)NN*128*4;            // 2 MB
  unsigned short* WbT  = (unsigned short*)p; p += (size_t)NHEAD*HID*F_IN*2;    // 1 MB
  unsigned short* WhT  = (unsigned short*)p; p += (size_t)NHEAD*HID*NN*2;      // 4 MB
  unsigned short* hbuf = (unsigned short*)p; p += (size_t)NN*NHEAD*HID*2;      // 4 MB
  unsigned short* WoT  = (unsigned short*)p; p += (size_t)48*NHEAD*HID*2;      // 48 KB
  unsigned short* WhT2 = (unsigned short*)p; p += (size_t)48*NN*2;             // 384 KB
  float* srcv = (float*)p; p += (size_t)NHEAD*NN*4;
  float* dstv = (float*)p; p += (size_t)NHEAD*NN*4;
  float* maxd = (float*)p; p += 256;
  float* s2   = (float*)p; p += (size_t)NN*4;
  float* d2   = (float*)p; p += (size_t)NN*4;
  float* m2   = (float*)p; p += 256;
  float* part = (float*)p; p += (size_t)8*NN*64*4;                             // 8 MB

  pack_adj_k<<<(NN*NN)/256, 256, 0, stream>>>(adj, bmT);
  cast_W_k<<<dim3(F_IN/64, NHEAD), 256, 0, stream>>>(W, WbT);
  cast_Wo_k<<<96, 256, 0, stream>>>(W_out, WoT);
  gemm1_k<<<dim3(NN/64, NHEAD), 256, 0, stream>>>(x, WbT, WhT, a_src, a_dst, srcv, dstv);
  maxred_k<<<NHEAD, 256, 0, stream>>>(dstv, maxd);
  agg_mfma_k<4, 64, false, true><<<dim3(NN/32, NHEAD), 256, 0, stream>>>(bmT, WhT, srcv, dstv, maxd, hbuf);
  gemm2_k<<<NN/64, 256, 0, stream>>>(hbuf, WoT, aos, aod, WhT2, s2, d2);
  maxred_k<<<1, 256, 0, stream>>>(d2, m2);
  agg_mfma_k<3, 8, true, false><<<dim3(NN/32, 8), 256, 0, stream>>>(bmT, WhT2, s2, d2, m2, part);
  final_k<<<NN/4, 256, 0, stream>>>(part, out);
}

// Round 6
// 163.894 us; speedup vs baseline: 5.7963x; 1.0644x over previous
//
#include <hip/hip_runtime.h>

#define NN 4096
#define F_IN 1024
#define NHEAD 8
#define HID 64
#define NCLS 40
#define LOG2E 1.44269504f

typedef float f32x4 __attribute__((ext_vector_type(4)));
typedef short s16x8 __attribute__((ext_vector_type(8)));

__device__ __forceinline__ unsigned short f2bf(float f){  // RNE float->bf16
  unsigned u = __float_as_uint(f);
  return (unsigned short)((u + 0x7fffu + ((u >> 16) & 1u)) >> 16);
}
__device__ __forceinline__ unsigned cvtpk(float lo, float hi){  // packed bf16 pair
  unsigned r; asm("v_cvt_pk_bf16_f32 %0, %1, %2" : "=v"(r) : "v"(lo), "v"(hi)); return r;
}

// ---------------- pack adjacency -> word-transposed bitmask ----------------
__global__ __launch_bounds__(256) void pack_adj_k(const int* __restrict__ adj, unsigned* __restrict__ bmT){
  int gid = blockIdx.x*256 + threadIdx.x;
  int lane = threadIdx.x & 63;
  unsigned long long m = __ballot(adj[gid] > 0);
  int w = gid >> 5, i = w >> 7, jw = w & 127;
  if (lane == 0)       bmT[(size_t)jw*NN + i] = (unsigned)m;
  else if (lane == 32) bmT[(size_t)jw*NN + i] = (unsigned)(m >> 32);
}

// ---------------- WbT[h][o][k] = bf16(W[h][k][o]) ----------------
__global__ __launch_bounds__(256) void cast_W_k(const float* __restrict__ W, unsigned short* __restrict__ WbT){
  __shared__ float T[64][65];
  const int h = blockIdx.y, k0 = blockIdx.x*64, t = threadIdx.x;
  for (int idx = t; idx < 1024; idx += 256){
    int k = idx >> 4, c4 = idx & 15;
    *(float4*)&T[k][c4*4] = *(const float4*)&W[((size_t)h*F_IN + k0 + k)*HID + c4*4];
  }
  __syncthreads();
  for (int idx = t; idx < 512; idx += 256){
    int o = idx >> 3, ch = idx & 7;
    s16x8 v;
    #pragma unroll
    for (int e = 0; e < 8; ++e) v[e] = (short)f2bf(T[ch*8 + e][o]);
    *(s16x8*)&WbT[((size_t)h*HID + o)*F_IN + k0 + ch*8] = v;
  }
}

// ---------------- WoT[c][k] = bf16(W_out[k][c]), rows 40..47 zero ----------------
__global__ __launch_bounds__(256) void cast_Wo_k(const float* __restrict__ Wout, unsigned short* __restrict__ WoT){
  int idx = blockIdx.x*256 + threadIdx.x;   // 48*512
  int cc = idx >> 9, k = idx & 511;
  WoT[idx] = (cc < NCLS) ? f2bf(Wout[(size_t)k*NCLS + cc]) : (unsigned short)0;
}

// ---------------- gemm1: WhT[h][o][n] bf16 = (x@W)^T ; srcv/dstv fused epilogue ----------------
__global__ __launch_bounds__(256) void gemm1_k(const float* __restrict__ x,
    const unsigned short* __restrict__ WbT, unsigned short* __restrict__ WhT,
    const float* __restrict__ a_src, const float* __restrict__ a_dst,
    float* __restrict__ srcv, float* __restrict__ dstv){
  __shared__ unsigned short xS[64][72];
  __shared__ unsigned short wS[64][72];
  const int t = threadIdx.x, l = t & 63, wv = t >> 6, g = l >> 4, c = l & 15;
  const int h = blockIdx.y, n0 = blockIdx.x * 64;
  f32x4 acc[4] = {};
  for (int k0 = 0; k0 < F_IN; k0 += 64){
    __syncthreads();
    #pragma unroll
    for (int p = 0; p < 4; ++p){
      int idx = t + p*256, row = idx >> 4, c4 = idx & 15;
      float4 v = *(const float4*)&x[(size_t)(n0+row)*F_IN + k0 + c4*4];
      *(uint2*)&xS[row][c4*4] = make_uint2(cvtpk(v.x, v.y), cvtpk(v.z, v.w));
    }
    #pragma unroll
    for (int p = 0; p < 2; ++p){
      int idx = t + p*256, o = idx >> 3, ch = idx & 7;
      *(s16x8*)&wS[o][ch*8] = *(const s16x8*)&WbT[(size_t)(h*HID + o)*F_IN + k0 + ch*8];
    }
    __syncthreads();
    #pragma unroll
    for (int ks = 0; ks < 2; ++ks){
      s16x8 av = *(const s16x8*)&xS[wv*16 + c][ks*32 + g*8];
      #pragma unroll
      for (int ct = 0; ct < 4; ++ct){
        s16x8 bv = *(const s16x8*)&wS[ct*16 + c][ks*32 + g*8];
        acc[ct] = __builtin_amdgcn_mfma_f32_16x16x32_bf16(av, bv, acc[ct], 0, 0, 0);
      }
    }
  }
  float asv[4], adv[4];
  #pragma unroll
  for (int ct = 0; ct < 4; ++ct){ asv[ct] = a_src[h*HID + ct*16 + c]; adv[ct] = a_dst[h*HID + ct*16 + c]; }
  #pragma unroll
  for (int r = 0; r < 4; ++r){
    float ps = acc[0][r]*asv[0] + acc[1][r]*asv[1] + acc[2][r]*asv[2] + acc[3][r]*asv[3];
    float pd = acc[0][r]*adv[0] + acc[1][r]*adv[1] + acc[2][r]*adv[2] + acc[3][r]*adv[3];
    #pragma unroll
    for (int off = 1; off < 16; off <<= 1){ ps += __shfl_xor(ps, off); pd += __shfl_xor(pd, off); }
    if (c == 0){ int n = n0 + wv*16 + g*4 + r; srcv[h*NN + n] = ps; dstv[h*NN + n] = pd; }
  }
  __syncthreads();
  #pragma unroll
  for (int ct = 0; ct < 4; ++ct)
    *(uint2*)&xS[ct*16 + c][wv*16 + g*4] = make_uint2(cvtpk(acc[ct][0], acc[ct][1]), cvtpk(acc[ct][2], acc[ct][3]));
  __syncthreads();
  #pragma unroll
  for (int p = 0; p < 2; ++p){
    int idx = t + p*256, o = idx >> 3, ch = idx & 7;
    *(s16x8*)&WhT[(size_t)(h*HID + o)*NN + n0 + ch*8] = *(const s16x8*)&xS[o][ch*8];
  }
}

// ---------------- per-4096-segment max reduce ----------------
__global__ __launch_bounds__(256) void maxred_k(const float* __restrict__ in, float* __restrict__ out){
  __shared__ float red[4];
  const float* p = in + (size_t)blockIdx.x*NN;
  float m = -3.0e38f;
  for (int i = threadIdx.x; i < NN; i += 256) m = fmaxf(m, p[i]);
  #pragma unroll
  for (int off = 32; off; off >>= 1) m = fmaxf(m, __shfl_xor(m, off));
  if ((threadIdx.x & 63) == 0) red[threadIdx.x >> 6] = m;
  __syncthreads();
  if (threadIdx.x == 0) out[blockIdx.x] = fmaxf(fmaxf(red[0], red[1]), fmaxf(red[2], red[3]));
}

// ---------------- MFMA masked-softmax aggregate (round-3 structure, factorized P) ----------------
// Block: 32 rows (i0..i0+31) x one head; 4 waves = j-parity tl(2) x row-half rH(2).
// p_ij = bit * min(max(A_i*B_j, C_i*D_j), 1); (B,D) staged in dS. Row sums via ones-MFMA.
template<int NCT, int NJT, bool CHUNKED, bool DO_ELU>
__global__ __launch_bounds__(256) void agg_mfma_k(
    const unsigned* __restrict__ bmT, const unsigned short* __restrict__ VT,
    const float* __restrict__ srcv, const float* __restrict__ dstv,
    const float* __restrict__ maxp, void* __restrict__ outp)
{
  __shared__ unsigned short vS[2][NCT*16][72];
  __shared__ float2 dS[2][64];
  __shared__ unsigned bitS[2][2][32];
  const int t = threadIdx.x, l = t & 63, wv = t >> 6, g = l >> 4, c = l & 15;
  const int h   = CHUNKED ? 0 : blockIdx.y;
  const int jt0 = CHUNKED ? blockIdx.y * NJT : 0;
  const int i0 = blockIdx.x * 32;
  const int tl = wv >> 1, rH = wv & 1;
  const int lr = rH*16 + c;
  const float sr = srcv[h*NN + i0 + lr];
  const float mx = maxp[CHUNKED ? 0 : h];
  const float tm = sr + mx;
  const float mi2 = fmaxf(tm, 0.2f*tm) * LOG2E;
  const float Af = exp2f(fmaf(sr, LOG2E, -mi2));
  const float Cf = exp2f(fmaf(0.2f*sr, LOG2E, -mi2));
  const unsigned short* vb = VT + (size_t)h*HID*NN;

  f32x4 acc[NCT] = {};
  f32x4 accs = {};
  s16x8 ones;
  #pragma unroll
  for (int e = 0; e < 8; ++e) ones[e] = (short)0x3F80;

  s16x8 vreg[NCT]; float2 dreg = make_float2(0.f, 0.f); unsigned breg = 0;
  auto loadRegs = [&](int jt){
    #pragma unroll
    for (int p = 0; p < NCT; ++p){
      int u = t + p*256;
      int tt = u / (NCT*128), rem = u % (NCT*128);
      int o = rem >> 3, chk = rem & 7;
      vreg[p] = *(const s16x8*)&vb[(size_t)o*NN + (jt+tt)*64 + chk*8];
    }
    if (t < 128){
      float d = dstv[h*NN + (jt + (t>>6))*64 + (t&63)];
      dreg = make_float2(exp2f(d*LOG2E), exp2f(0.2f*d*LOG2E));
    }
    else { int u = t - 128; breg = bmT[(size_t)((jt + (u>>6))*2 + ((u>>5)&1))*NN + i0 + (u&31)]; }
  };
  auto writeLDS = [&](){
    #pragma unroll
    for (int p = 0; p < NCT; ++p){
      int u = t + p*256;
      int tt = u / (NCT*128), rem = u % (NCT*128);
      int o = rem >> 3, chk = rem & 7;
      *(s16x8*)&vS[tt][o][chk*8] = vreg[p];
    }
    if (t < 128) dS[t>>6][t&63] = dreg;
    else { int u = t - 128; bitS[u>>6][(u>>5)&1][u&31] = breg; }
  };

  loadRegs(jt0);
  for (int jj = 0; jj < NJT; jj += 2){
    __syncthreads();
    writeLDS();
    __syncthreads();
    if (jj + 2 < NJT) loadRegs(jt0 + jj + 2);
    #pragma unroll
    for (int ks = 0; ks < 2; ++ks){
      unsigned wb = (bitS[tl][ks][lr] >> (g*8)) & 0xffu;
      const float4 qa = *(const float4*)&dS[tl][ks*32 + g*8];
      const float4 qb = *(const float4*)&dS[tl][ks*32 + g*8 + 2];
      const float4 qc = *(const float4*)&dS[tl][ks*32 + g*8 + 4];
      const float4 qd = *(const float4*)&dS[tl][ks*32 + g*8 + 6];
      float p0 = (wb & 1u)   ? fminf(fmaxf(Af*qa.x, Cf*qa.y), 1.f) : 0.f;
      float p1 = (wb & 2u)   ? fminf(fmaxf(Af*qa.z, Cf*qa.w), 1.f) : 0.f;
      float p2 = (wb & 4u)   ? fminf(fmaxf(Af*qb.x, Cf*qb.y), 1.f) : 0.f;
      float p3 = (wb & 8u)   ? fminf(fmaxf(Af*qb.z, Cf*qb.w), 1.f) : 0.f;
      float p4 = (wb & 16u)  ? fminf(fmaxf(Af*qc.x, Cf*qc.y), 1.f) : 0.f;
      float p5 = (wb & 32u)  ? fminf(fmaxf(Af*qc.z, Cf*qc.w), 1.f) : 0.f;
      float p6 = (wb & 64u)  ? fminf(fmaxf(Af*qd.x, Cf*qd.y), 1.f) : 0.f;
      float p7 = (wb & 128u) ? fminf(fmaxf(Af*qd.z, Cf*qd.w), 1.f) : 0.f;
      s16x8 af;
      ((unsigned*)&af)[0] = cvtpk(p0, p1);
      ((unsigned*)&af)[1] = cvtpk(p2, p3);
      ((unsigned*)&af)[2] = cvtpk(p4, p5);
      ((unsigned*)&af)[3] = cvtpk(p6, p7);
      #pragma unroll
      for (int ct = 0; ct < NCT; ++ct){
        s16x8 bv = *(const s16x8*)&vS[tl][ct*16 + c][ks*32 + g*8];
        acc[ct] = __builtin_amdgcn_mfma_f32_16x16x32_bf16(af, bv, acc[ct], 0, 0, 0);
      }
      accs = __builtin_amdgcn_mfma_f32_16x16x32_bf16(af, ones, accs, 0, 0, 0);
    }
  }
  // merge j-parity wave pairs via LDS
  __syncthreads();
  float* mrg = (float*)&vS[0][0][0];
  constexpr int S = (NCT + 1) * 4;
  if (tl == 1){
    int base = (rH*64 + l) * S;
    #pragma unroll
    for (int ct = 0; ct < NCT; ++ct)
      #pragma unroll
      for (int r = 0; r < 4; ++r) mrg[base + ct*4 + r] = acc[ct][r];
    #pragma unroll
    for (int r = 0; r < 4; ++r) mrg[base + NCT*4 + r] = accs[r];
  }
  __syncthreads();
  if (tl == 0){
    int base = (rH*64 + l) * S;
    #pragma unroll
    for (int ct = 0; ct < NCT; ++ct)
      #pragma unroll
      for (int r = 0; r < 4; ++r) acc[ct][r] += mrg[base + ct*4 + r];
    #pragma unroll
    for (int r = 0; r < 4; ++r) accs[r] += mrg[base + NCT*4 + r];
    if (!CHUNKED){
      unsigned short* ob = (unsigned short*)outp;
      #pragma unroll
      for (int r = 0; r < 4; ++r){
        float inv = 1.f / fmaxf(accs[r], 1e-30f);
        int row = i0 + rH*16 + g*4 + r;
        #pragma unroll
        for (int ct = 0; ct < NCT; ++ct){
          float v = acc[ct][r] * inv;
          if (DO_ELU) v = v > 0.f ? v : __expf(v) - 1.f;
          ob[(size_t)row*(NHEAD*HID) + h*HID + ct*16 + c] = f2bf(v);
        }
      }
    } else {
      float* ob = (float*)outp + (size_t)blockIdx.y * NN * 64;
      #pragma unroll
      for (int r = 0; r < 4; ++r){
        int row = i0 + rH*16 + g*4 + r;
        #pragma unroll
        for (int ct = 0; ct < NCT; ++ct)
          ob[(size_t)row*64 + ct*16 + c] = acc[ct][r];
        if (c == 0) ob[(size_t)row*64 + 48] = accs[r];
      }
    }
  }
}

// ---------------- gemm2: WhT2[c][n] bf16 = (h_bf16 @ W_out)^T ; s2/d2 fused ----------------
__global__ __launch_bounds__(256) void gemm2_k(const unsigned short* __restrict__ hb,
    const unsigned short* __restrict__ WoT, const float* __restrict__ aos, const float* __restrict__ aod,
    unsigned short* __restrict__ WhT2, float* __restrict__ s2, float* __restrict__ d2){
  __shared__ unsigned short aS[64][72];
  __shared__ unsigned short bS[48][72];
  const int t = threadIdx.x, l = t & 63, wv = t >> 6, g = l >> 4, c = l & 15;
  const int n0 = blockIdx.x * 64;
  f32x4 acc[3] = {};
  for (int k0 = 0; k0 < NHEAD*HID; k0 += 64){
    __syncthreads();
    #pragma unroll
    for (int p = 0; p < 2; ++p){
      int u = t + p*256, o = u >> 3, ch = u & 7;
      *(s16x8*)&aS[o][ch*8] = *(const s16x8*)&hb[(size_t)(n0+o)*(NHEAD*HID) + k0 + ch*8];
    }
    for (int u = t; u < 384; u += 256){
      int o = u >> 3, ch = u & 7;
      *(s16x8*)&bS[o][ch*8] = *(const s16x8*)&WoT[(size_t)o*(NHEAD*HID) + k0 + ch*8];
    }
    __syncthreads();
    #pragma unroll
    for (int ks = 0; ks < 2; ++ks){
      s16x8 av = *(const s16x8*)&aS[wv*16 + c][ks*32 + g*8];
      #pragma unroll
      for (int ct = 0; ct < 3; ++ct){
        s16x8 bv = *(const s16x8*)&bS[ct*16 + c][ks*32 + g*8];
        acc[ct] = __builtin_amdgcn_mfma_f32_16x16x32_bf16(av, bv, acc[ct], 0, 0, 0);
      }
    }
  }
  float asv[3], adv[3];
  #pragma unroll
  for (int ct = 0; ct < 3; ++ct){
    int col = ct*16 + c;
    asv[ct] = (col < NCLS) ? aos[col] : 0.f;
    adv[ct] = (col < NCLS) ? aod[col] : 0.f;
  }
  #pragma unroll
  for (int r = 0; r < 4; ++r){
    float ps = acc[0][r]*asv[0] + acc[1][r]*asv[1] + acc[2][r]*asv[2];
    float pd = acc[0][r]*adv[0] + acc[1][r]*adv[1] + acc[2][r]*adv[2];
    #pragma unroll
    for (int off = 1; off < 16; off <<= 1){ ps += __shfl_xor(ps, off); pd += __shfl_xor(pd, off); }
    if (c == 0){ int n = n0 + wv*16 + g*4 + r; s2[n] = ps; d2[n] = pd; }
  }
  __syncthreads();
  #pragma unroll
  for (int ct = 0; ct < 3; ++ct)
    *(uint2*)&bS[ct*16 + c][wv*16 + g*4] = make_uint2(cvtpk(acc[ct][0], acc[ct][1]), cvtpk(acc[ct][2], acc[ct][3]));
  __syncthreads();
  for (int u = t; u < 384; u += 256){
    int o = u >> 3, ch = u & 7;
    *(s16x8*)&WhT2[(size_t)o*NN + n0 + ch*8] = *(const s16x8*)&bS[o][ch*8];
  }
}

// ---------------- merge 8 chunks + elu + row log_softmax ----------------
__global__ __launch_bounds__(256) void final_k(const float* __restrict__ part, float* __restrict__ out){
  const int wid = (blockIdx.x*256 + threadIdx.x) >> 6;
  const int c = threadIdx.x & 63;
  float acc = 0.f, rs = 0.f;
  #pragma unroll
  for (int ch = 0; ch < 8; ++ch){
    const float* pb = part + ((size_t)ch*NN + wid)*64;
    if (c < 48) acc += pb[c];
    rs += pb[48];
  }
  float v = acc / fmaxf(rs, 1e-30f);
  float e = v > 0.f ? v : __expf(v) - 1.f;
  float ev = (c < NCLS) ? e : -3.0e38f;
  float m = ev;
  #pragma unroll
  for (int off = 32; off; off >>= 1) m = fmaxf(m, __shfl_xor(m, off));
  float ex = (c < NCLS) ? __expf(e - m) : 0.f;
  float s = ex;
  #pragma unroll
  for (int off = 32; off; off >>= 1) s += __shfl_xor(s, off);
  if (c < NCLS) out[(size_t)wid*NCLS + c] = e - m - __logf(s);
}

extern "C" void kernel_launch(void* const* d_in, const int* in_sizes, int n_in,
                              void* d_out, int out_size, void* d_ws, size_t ws_size,
                              hipStream_t stream){
  (void)in_sizes; (void)n_in; (void)out_size; (void)ws_size;
  const float* x     = (const float*)d_in[0];
  const int*   adj   = (const int*)  d_in[1];
  const float* W     = (const float*)d_in[2];
  const float* a_src = (const float*)d_in[3];
  const float* a_dst = (const float*)d_in[4];
  const float* W_out = (const float*)d_in[5];
  const float* aos   = (const float*)d_in[6];
  const float* aod   = (const float*)d_in[7];
  float* out = (float*)d_out;

  char* p = (char*)d_ws;
  unsigned* bmT        = (unsigned*)p;       p += (size_t)NN*128*4;            // 2 MB
  unsigned short* WbT  = (unsigned short*)p; p += (size_t)NHEAD*HID*F_IN*2;    // 1 MB
  unsigned short* WhT  = (unsigned short*)p; p += (size_t)NHEAD*HID*NN*2;      // 4 MB
  unsigned short* hbuf = (unsigned short*)p; p += (size_t)NN*NHEAD*HID*2;      // 4 MB
  unsigned short* WoT  = (unsigned short*)p; p += (size_t)48*NHEAD*HID*2;      // 48 KB
  unsigned short* WhT2 = (unsigned short*)p; p += (size_t)48*NN*2;             // 384 KB
  float* srcv = (float*)p; p += (size_t)NHEAD*NN*4;
  float* dstv = (float*)p; p += (size_t)NHEAD*NN*4;
  float* maxd = (float*)p; p += 256;
  float* s2   = (float*)p; p += (size_t)NN*4;
  float* d2   = (float*)p; p += (size_t)NN*4;
  float* m2   = (float*)p; p += 256;
  float* part = (float*)p; p += (size_t)8*NN*64*4;                             // 8 MB

  pack_adj_k<<<(NN*NN)/256, 256, 0, stream>>>(adj, bmT);
  cast_W_k<<<dim3(F_IN/64, NHEAD), 256, 0, stream>>>(W, WbT);
  cast_Wo_k<<<96, 256, 0, stream>>>(W_out, WoT);
  gemm1_k<<<dim3(NN/64, NHEAD), 256, 0, stream>>>(x, WbT, WhT, a_src, a_dst, srcv, dstv);
  maxred_k<<<NHEAD, 256, 0, stream>>>(dstv, maxd);
  agg_mfma_k<4, 64, false, true><<<dim3(NN/32, NHEAD), 256, 0, stream>>>(bmT, WhT, srcv, dstv, maxd, hbuf);
  gemm2_k<<<NN/64, 256, 0, stream>>>(hbuf, WoT, aos, aod, WhT2, s2, d2);
  maxred_k<<<1, 256, 0, stream>>>(d2, m2);
  agg_mfma_k<3, 8, true, false><<<dim3(NN/32, 8), 256, 0, stream>>>(bmT, WhT2, s2, d2, m2, part);
  final_k<<<NN/4, 256, 0, stream>>>(part, out);
}

// Round 7
// 159.807 us; speedup vs baseline: 5.9446x; 1.0256x over previous
//
#include <hip/hip_runtime.h>

#define NN 4096
#define F_IN 1024
#define NHEAD 8
#define HID 64
#define NCLS 40
#define LOG2E 1.44269504f

typedef float f32x4 __attribute__((ext_vector_type(4)));
typedef float f32x2 __attribute__((ext_vector_type(2)));
typedef short s16x8 __attribute__((ext_vector_type(8)));

// XOR-swizzled halfword index within a [R][64]-hw (128B-row) LDS tile:
// byte ^= (row&7)<<4  ->  halfword col ^= (row&7)<<3. 16B-chunk bijective per row.
#define SWZ(r,c) (((r)*64) + ((c) ^ (((r)&7)<<3)))

__device__ __forceinline__ unsigned short f2bf(float f){  // RNE float->bf16
  unsigned u = __float_as_uint(f);
  return (unsigned short)((u + 0x7fffu + ((u >> 16) & 1u)) >> 16);
}
__device__ __forceinline__ unsigned cvtpk(float lo, float hi){  // packed bf16 pair
  unsigned r; asm("v_cvt_pk_bf16_f32 %0, %1, %2" : "=v"(r) : "v"(lo), "v"(hi)); return r;
}
__device__ __forceinline__ f32x2 pkmul(f32x2 a, f32x2 b){  // packed fp32 dual mul
  f32x2 r; asm("v_pk_mul_f32 %0, %1, %2" : "=v"(r) : "v"(a), "v"(b)); return r;
}

// ---------------- pack adjacency -> word-transposed bitmask ----------------
__global__ __launch_bounds__(256) void pack_adj_k(const int* __restrict__ adj, unsigned* __restrict__ bmT){
  int gid = blockIdx.x*256 + threadIdx.x;
  int lane = threadIdx.x & 63;
  unsigned long long m = __ballot(adj[gid] > 0);
  int w = gid >> 5, i = w >> 7, jw = w & 127;
  if (lane == 0)       bmT[(size_t)jw*NN + i] = (unsigned)m;
  else if (lane == 32) bmT[(size_t)jw*NN + i] = (unsigned)(m >> 32);
}

// ---------------- WbT[h][o][k] = bf16(W[h][k][o]) ----------------
__global__ __launch_bounds__(256) void cast_W_k(const float* __restrict__ W, unsigned short* __restrict__ WbT){
  __shared__ float T[64][65];
  const int h = blockIdx.y, k0 = blockIdx.x*64, t = threadIdx.x;
  for (int idx = t; idx < 1024; idx += 256){
    int k = idx >> 4, c4 = idx & 15;
    *(float4*)&T[k][c4*4] = *(const float4*)&W[((size_t)h*F_IN + k0 + k)*HID + c4*4];
  }
  __syncthreads();
  for (int idx = t; idx < 512; idx += 256){
    int o = idx >> 3, ch = idx & 7;
    s16x8 v;
    #pragma unroll
    for (int e = 0; e < 8; ++e) v[e] = (short)f2bf(T[ch*8 + e][o]);
    *(s16x8*)&WbT[((size_t)h*HID + o)*F_IN + k0 + ch*8] = v;
  }
}

// ---------------- WoT[c][k] = bf16(W_out[k][c]), rows 40..47 zero ----------------
__global__ __launch_bounds__(256) void cast_Wo_k(const float* __restrict__ Wout, unsigned short* __restrict__ WoT){
  int idx = blockIdx.x*256 + threadIdx.x;   // 48*512
  int cc = idx >> 9, k = idx & 511;
  WoT[idx] = (cc < NCLS) ? f2bf(Wout[(size_t)k*NCLS + cc]) : (unsigned short)0;
}

// ---------------- gemm1: WhT[h][o][n] bf16 = (x@W)^T ; srcv/dstv fused epilogue ----------------
__global__ __launch_bounds__(256) void gemm1_k(const float* __restrict__ x,
    const unsigned short* __restrict__ WbT, unsigned short* __restrict__ WhT,
    const float* __restrict__ a_src, const float* __restrict__ a_dst,
    float* __restrict__ srcv, float* __restrict__ dstv){
  __shared__ unsigned short xS[64*64];
  __shared__ unsigned short wS[64*64];
  const int t = threadIdx.x, l = t & 63, wv = t >> 6, g = l >> 4, c = l & 15;
  const int h = blockIdx.y, n0 = blockIdx.x * 64;
  f32x4 acc[4] = {};
  for (int k0 = 0; k0 < F_IN; k0 += 64){
    __syncthreads();
    #pragma unroll
    for (int p = 0; p < 4; ++p){
      int idx = t + p*256, row = idx >> 4, c4 = idx & 15;
      float4 v = *(const float4*)&x[(size_t)(n0+row)*F_IN + k0 + c4*4];
      *(uint2*)&xS[SWZ(row, c4*4)] = make_uint2(cvtpk(v.x, v.y), cvtpk(v.z, v.w));
    }
    #pragma unroll
    for (int p = 0; p < 2; ++p){
      int idx = t + p*256, o = idx >> 3, ch = idx & 7;
      *(s16x8*)&wS[SWZ(o, ch*8)] = *(const s16x8*)&WbT[(size_t)(h*HID + o)*F_IN + k0 + ch*8];
    }
    __syncthreads();
    #pragma unroll
    for (int ks = 0; ks < 2; ++ks){
      s16x8 av = *(const s16x8*)&xS[SWZ(wv*16 + c, ks*32 + g*8)];
      #pragma unroll
      for (int ct = 0; ct < 4; ++ct){
        s16x8 bv = *(const s16x8*)&wS[SWZ(ct*16 + c, ks*32 + g*8)];
        acc[ct] = __builtin_amdgcn_mfma_f32_16x16x32_bf16(av, bv, acc[ct], 0, 0, 0);
      }
    }
  }
  float asv[4], adv[4];
  #pragma unroll
  for (int ct = 0; ct < 4; ++ct){ asv[ct] = a_src[h*HID + ct*16 + c]; adv[ct] = a_dst[h*HID + ct*16 + c]; }
  #pragma unroll
  for (int r = 0; r < 4; ++r){
    float ps = acc[0][r]*asv[0] + acc[1][r]*asv[1] + acc[2][r]*asv[2] + acc[3][r]*asv[3];
    float pd = acc[0][r]*adv[0] + acc[1][r]*adv[1] + acc[2][r]*adv[2] + acc[3][r]*adv[3];
    #pragma unroll
    for (int off = 1; off < 16; off <<= 1){ ps += __shfl_xor(ps, off); pd += __shfl_xor(pd, off); }
    if (c == 0){ int n = n0 + wv*16 + g*4 + r; srcv[h*NN + n] = ps; dstv[h*NN + n] = pd; }
  }
  __syncthreads();
  #pragma unroll
  for (int ct = 0; ct < 4; ++ct)
    *(uint2*)&xS[SWZ(ct*16 + c, wv*16 + g*4)] = make_uint2(cvtpk(acc[ct][0], acc[ct][1]), cvtpk(acc[ct][2], acc[ct][3]));
  __syncthreads();
  #pragma unroll
  for (int p = 0; p < 2; ++p){
    int idx = t + p*256, o = idx >> 3, ch = idx & 7;
    *(s16x8*)&WhT[(size_t)(h*HID + o)*NN + n0 + ch*8] = *(const s16x8*)&xS[SWZ(o, ch*8)];
  }
}

// ---------------- per-4096-segment max reduce ----------------
__global__ __launch_bounds__(256) void maxred_k(const float* __restrict__ in, float* __restrict__ out){
  __shared__ float red[4];
  const float* p = in + (size_t)blockIdx.x*NN;
  float m = -3.0e38f;
  for (int i = threadIdx.x; i < NN; i += 256) m = fmaxf(m, p[i]);
  #pragma unroll
  for (int off = 32; off; off >>= 1) m = fmaxf(m, __shfl_xor(m, off));
  if ((threadIdx.x & 63) == 0) red[threadIdx.x >> 6] = m;
  __syncthreads();
  if (threadIdx.x == 0) out[blockIdx.x] = fmaxf(fmaxf(red[0], red[1]), fmaxf(red[2], red[3]));
}

// ---------------- MFMA masked-softmax aggregate (factorized P, swizzled LDS) ----------------
// Block: 32 rows x one head; 4 waves = j-parity tl(2) x row-half rH(2).
// p_ij = bit * med3(A_i*B_j, C_i*D_j, 1); (B,D) staged in dS. Row sums via ones-MFMA.
template<int NCT, int NJT, bool CHUNKED, bool DO_ELU>
__global__ __launch_bounds__(256) void agg_mfma_k(
    const unsigned* __restrict__ bmT, const unsigned short* __restrict__ VT,
    const float* __restrict__ srcv, const float* __restrict__ dstv,
    const float* __restrict__ maxp, void* __restrict__ outp)
{
  __shared__ unsigned short vS[2][NCT*16*64];
  __shared__ float2 dS[2][64];
  __shared__ unsigned bitS[2][2][32];
  const int t = threadIdx.x, l = t & 63, wv = t >> 6, g = l >> 4, c = l & 15;
  const int h   = CHUNKED ? 0 : blockIdx.y;
  const int jt0 = CHUNKED ? blockIdx.y * NJT : 0;
  const int i0 = blockIdx.x * 32;
  const int tl = wv >> 1, rH = wv & 1;
  const int lr = rH*16 + c;
  const float sr = srcv[h*NN + i0 + lr];
  const float mx = maxp[CHUNKED ? 0 : h];
  const float tm = sr + mx;
  const float mi2 = fmaxf(tm, 0.2f*tm) * LOG2E;
  f32x2 ac2;
  ac2[0] = exp2f(fmaf(sr, LOG2E, -mi2));        // A_i
  ac2[1] = exp2f(fmaf(0.2f*sr, LOG2E, -mi2));   // C_i
  const unsigned short* vb = VT + (size_t)h*HID*NN;

  f32x4 acc[NCT] = {};
  f32x4 accs = {};
  s16x8 ones;
  #pragma unroll
  for (int e = 0; e < 8; ++e) ones[e] = (short)0x3F80;

  s16x8 vreg[NCT]; float2 dreg = make_float2(0.f, 0.f); unsigned breg = 0;
  auto loadRegs = [&](int jt){
    #pragma unroll
    for (int p = 0; p < NCT; ++p){
      int u = t + p*256;
      int tt = u / (NCT*128), rem = u % (NCT*128);
      int o = rem >> 3, chk = rem & 7;
      vreg[p] = *(const s16x8*)&vb[(size_t)o*NN + (jt+tt)*64 + chk*8];
    }
    if (t < 128){
      float d = dstv[h*NN + (jt + (t>>6))*64 + (t&63)];
      dreg = make_float2(exp2f(d*LOG2E), exp2f(0.2f*d*LOG2E));
    }
    else { int u = t - 128; breg = bmT[(size_t)((jt + (u>>6))*2 + ((u>>5)&1))*NN + i0 + (u&31)]; }
  };
  auto writeLDS = [&](){
    #pragma unroll
    for (int p = 0; p < NCT; ++p){
      int u = t + p*256;
      int tt = u / (NCT*128), rem = u % (NCT*128);
      int o = rem >> 3, chk = rem & 7;
      *(s16x8*)&vS[tt][SWZ(o, chk*8)] = vreg[p];
    }
    if (t < 128) dS[t>>6][t&63] = dreg;
    else { int u = t - 128; bitS[u>>6][(u>>5)&1][u&31] = breg; }
  };

  loadRegs(jt0);
  for (int jj = 0; jj < NJT; jj += 2){
    __syncthreads();
    writeLDS();
    __syncthreads();
    if (jj + 2 < NJT) loadRegs(jt0 + jj + 2);
    #pragma unroll
    for (int ks = 0; ks < 2; ++ks){
      unsigned wb = (bitS[tl][ks][lr] >> (g*8)) & 0xffu;
      const f32x2* dr = (const f32x2*)&dS[tl][ks*32 + g*8];
      float q[8];
      #pragma unroll
      for (int e = 0; e < 8; ++e){
        f32x2 pr = pkmul(ac2, dr[e]);
        float m3 = __builtin_amdgcn_fmed3f(pr[0], pr[1], 1.0f);
        q[e] = (wb & (1u << e)) ? m3 : 0.f;
      }
      s16x8 af;
      ((unsigned*)&af)[0] = cvtpk(q[0], q[1]);
      ((unsigned*)&af)[1] = cvtpk(q[2], q[3]);
      ((unsigned*)&af)[2] = cvtpk(q[4], q[5]);
      ((unsigned*)&af)[3] = cvtpk(q[6], q[7]);
      #pragma unroll
      for (int ct = 0; ct < NCT; ++ct){
        s16x8 bv = *(const s16x8*)&vS[tl][SWZ(ct*16 + c, ks*32 + g*8)];
        acc[ct] = __builtin_amdgcn_mfma_f32_16x16x32_bf16(af, bv, acc[ct], 0, 0, 0);
      }
      accs = __builtin_amdgcn_mfma_f32_16x16x32_bf16(af, ones, accs, 0, 0, 0);
    }
  }
  // merge j-parity wave pairs via LDS
  __syncthreads();
  float* mrg = (float*)&vS[0][0];
  constexpr int S = (NCT + 1) * 4;
  if (tl == 1){
    int base = (rH*64 + l) * S;
    #pragma unroll
    for (int ct = 0; ct < NCT; ++ct)
      #pragma unroll
      for (int r = 0; r < 4; ++r) mrg[base + ct*4 + r] = acc[ct][r];
    #pragma unroll
    for (int r = 0; r < 4; ++r) mrg[base + NCT*4 + r] = accs[r];
  }
  __syncthreads();
  if (tl == 0){
    int base = (rH*64 + l) * S;
    #pragma unroll
    for (int ct = 0; ct < NCT; ++ct)
      #pragma unroll
      for (int r = 0; r < 4; ++r) acc[ct][r] += mrg[base + ct*4 + r];
    #pragma unroll
    for (int r = 0; r < 4; ++r) accs[r] += mrg[base + NCT*4 + r];
    if (!CHUNKED){
      unsigned short* ob = (unsigned short*)outp;
      #pragma unroll
      for (int r = 0; r < 4; ++r){
        float inv = 1.f / fmaxf(accs[r], 1e-30f);
        int row = i0 + rH*16 + g*4 + r;
        #pragma unroll
        for (int ct = 0; ct < NCT; ++ct){
          float v = acc[ct][r] * inv;
          if (DO_ELU) v = v > 0.f ? v : __expf(v) - 1.f;
          ob[(size_t)row*(NHEAD*HID) + h*HID + ct*16 + c] = f2bf(v);
        }
      }
    } else {
      float* ob = (float*)outp + (size_t)blockIdx.y * NN * 64;
      #pragma unroll
      for (int r = 0; r < 4; ++r){
        int row = i0 + rH*16 + g*4 + r;
        #pragma unroll
        for (int ct = 0; ct < NCT; ++ct)
          ob[(size_t)row*64 + ct*16 + c] = acc[ct][r];
        if (c == 0) ob[(size_t)row*64 + 48] = accs[r];
      }
    }
  }
}

// ---------------- gemm2: WhT2[c][n] bf16 = (h_bf16 @ W_out)^T ; s2/d2 fused ----------------
__global__ __launch_bounds__(256) void gemm2_k(const unsigned short* __restrict__ hb,
    const unsigned short* __restrict__ WoT, const float* __restrict__ aos, const float* __restrict__ aod,
    unsigned short* __restrict__ WhT2, float* __restrict__ s2, float* __restrict__ d2){
  __shared__ unsigned short aS[64*64];
  __shared__ unsigned short bS[48*64];
  const int t = threadIdx.x, l = t & 63, wv = t >> 6, g = l >> 4, c = l & 15;
  const int n0 = blockIdx.x * 64;
  f32x4 acc[3] = {};
  for (int k0 = 0; k0 < NHEAD*HID; k0 += 64){
    __syncthreads();
    #pragma unroll
    for (int p = 0; p < 2; ++p){
      int u = t + p*256, o = u >> 3, ch = u & 7;
      *(s16x8*)&aS[SWZ(o, ch*8)] = *(const s16x8*)&hb[(size_t)(n0+o)*(NHEAD*HID) + k0 + ch*8];
    }
    for (int u = t; u < 384; u += 256){
      int o = u >> 3, ch = u & 7;
      *(s16x8*)&bS[SWZ(o, ch*8)] = *(const s16x8*)&WoT[(size_t)o*(NHEAD*HID) + k0 + ch*8];
    }
    __syncthreads();
    #pragma unroll
    for (int ks = 0; ks < 2; ++ks){
      s16x8 av = *(const s16x8*)&aS[SWZ(wv*16 + c, ks*32 + g*8)];
      #pragma unroll
      for (int ct = 0; ct < 3; ++ct){
        s16x8 bv = *(const s16x8*)&bS[SWZ(ct*16 + c, ks*32 + g*8)];
        acc[ct] = __builtin_amdgcn_mfma_f32_16x16x32_bf16(av, bv, acc[ct], 0, 0, 0);
      }
    }
  }
  float asv[3], adv[3];
  #pragma unroll
  for (int ct = 0; ct < 3; ++ct){
    int col = ct*16 + c;
    asv[ct] = (col < NCLS) ? aos[col] : 0.f;
    adv[ct] = (col < NCLS) ? aod[col] : 0.f;
  }
  #pragma unroll
  for (int r = 0; r < 4; ++r){
    float ps = acc[0][r]*asv[0] + acc[1][r]*asv[1] + acc[2][r]*asv[2];
    float pd = acc[0][r]*adv[0] + acc[1][r]*adv[1] + acc[2][r]*adv[2];
    #pragma unroll
    for (int off = 1; off < 16; off <<= 1){ ps += __shfl_xor(ps, off); pd += __shfl_xor(pd, off); }
    if (c == 0){ int n = n0 + wv*16 + g*4 + r; s2[n] = ps; d2[n] = pd; }
  }
  __syncthreads();
  #pragma unroll
  for (int ct = 0; ct < 3; ++ct)
    *(uint2*)&bS[SWZ(ct*16 + c, wv*16 + g*4)] = make_uint2(cvtpk(acc[ct][0], acc[ct][1]), cvtpk(acc[ct][2], acc[ct][3]));
  __syncthreads();
  for (int u = t; u < 384; u += 256){
    int o = u >> 3, ch = u & 7;
    *(s16x8*)&WhT2[(size_t)o*NN + n0 + ch*8] = *(const s16x8*)&bS[SWZ(o, ch*8)];
  }
}

// ---------------- merge 8 chunks + elu + row log_softmax ----------------
__global__ __launch_bounds__(256) void final_k(const float* __restrict__ part, float* __restrict__ out){
  const int wid = (blockIdx.x*256 + threadIdx.x) >> 6;
  const int c = threadIdx.x & 63;
  float acc = 0.f, rs = 0.f;
  #pragma unroll
  for (int ch = 0; ch < 8; ++ch){
    const float* pb = part + ((size_t)ch*NN + wid)*64;
    if (c < 48) acc += pb[c];
    rs += pb[48];
  }
  float v = acc / fmaxf(rs, 1e-30f);
  float e = v > 0.f ? v : __expf(v) - 1.f;
  float ev = (c < NCLS) ? e : -3.0e38f;
  float m = ev;
  #pragma unroll
  for (int off = 32; off; off >>= 1) m = fmaxf(m, __shfl_xor(m, off));
  float ex = (c < NCLS) ? __expf(e - m) : 0.f;
  float s = ex;
  #pragma unroll
  for (int off = 32; off; off >>= 1) s += __shfl_xor(s, off);
  if (c < NCLS) out[(size_t)wid*NCLS + c] = e - m - __logf(s);
}

extern "C" void kernel_launch(void* const* d_in, const int* in_sizes, int n_in,
                              void* d_out, int out_size, void* d_ws, size_t ws_size,
                              hipStream_t stream){
  (void)in_sizes; (void)n_in; (void)out_size; (void)ws_size;
  const float* x     = (const float*)d_in[0];
  const int*   adj   = (const int*)  d_in[1];
  const float* W     = (const float*)d_in[2];
  const float* a_src = (const float*)d_in[3];
  const float* a_dst = (const float*)d_in[4];
  const float* W_out = (const float*)d_in[5];
  const float* aos   = (const float*)d_in[6];
  const float* aod   = (const float*)d_in[7];
  float* out = (float*)d_out;

  char* p = (char*)d_ws;
  unsigned* bmT        = (unsigned*)p;       p += (size_t)NN*128*4;            // 2 MB
  unsigned short* WbT  = (unsigned short*)p; p += (size_t)NHEAD*HID*F_IN*2;    // 1 MB
  unsigned short* WhT  = (unsigned short*)p; p += (size_t)NHEAD*HID*NN*2;      // 4 MB
  unsigned short* hbuf = (unsigned short*)p; p += (size_t)NN*NHEAD*HID*2;      // 4 MB
  unsigned short* WoT  = (unsigned short*)p; p += (size_t)48*NHEAD*HID*2;      // 48 KB
  unsigned short* WhT2 = (unsigned short*)p; p += (size_t)48*NN*2;             // 384 KB
  float* srcv = (float*)p; p += (size_t)NHEAD*NN*4;
  float* dstv = (float*)p; p += (size_t)NHEAD*NN*4;
  float* maxd = (float*)p; p += 256;
  float* s2   = (float*)p; p += (size_t)NN*4;
  float* d2   = (float*)p; p += (size_t)NN*4;
  float* m2   = (float*)p; p += 256;
  float* part = (float*)p; p += (size_t)8*NN*64*4;                             // 8 MB

  pack_adj_k<<<(NN*NN)/256, 256, 0, stream>>>(adj, bmT);
  cast_W_k<<<dim3(F_IN/64, NHEAD), 256, 0, stream>>>(W, WbT);
  cast_Wo_k<<<96, 256, 0, stream>>>(W_out, WoT);
  gemm1_k<<<dim3(NN/64, NHEAD), 256, 0, stream>>>(x, WbT, WhT, a_src, a_dst, srcv, dstv);
  maxred_k<<<NHEAD, 256, 0, stream>>>(dstv, maxd);
  agg_mfma_k<4, 64, false, true><<<dim3(NN/32, NHEAD), 256, 0, stream>>>(bmT, WhT, srcv, dstv, maxd, hbuf);
  gemm2_k<<<NN/64, 256, 0, stream>>>(hbuf, WoT, aos, aod, WhT2, s2, d2);
  maxred_k<<<1, 256, 0, stream>>>(d2, m2);
  agg_mfma_k<3, 8, true, false><<<dim3(NN/32, 8), 256, 0, stream>>>(bmT, WhT2, s2, d2, m2, part);
  final_k<<<NN/4, 256, 0, stream>>>(part, out);
}

// Round 8
// 157.072 us; speedup vs baseline: 6.0481x; 1.0174x over previous
//
#include <hip/hip_runtime.h>

#define NN 4096
#define F_IN 1024
#define NHEAD 8
#define HID 64
#define NCLS 40
#define LOG2E 1.44269504f

typedef float f32x4 __attribute__((ext_vector_type(4)));
typedef float f32x2 __attribute__((ext_vector_type(2)));
typedef short s16x8 __attribute__((ext_vector_type(8)));

// XOR-swizzled halfword index within a [R][64]-hw (128B-row) LDS tile:
// byte ^= (row&7)<<4  ->  halfword col ^= (row&7)<<3. 16B-chunk bijective per row.
#define SWZ(r,c) (((r)*64) + ((c) ^ (((r)&7)<<3)))

__device__ __forceinline__ unsigned short f2bf(float f){  // RNE float->bf16
  unsigned u = __float_as_uint(f);
  return (unsigned short)((u + 0x7fffu + ((u >> 16) & 1u)) >> 16);
}
__device__ __forceinline__ unsigned cvtpk(float lo, float hi){  // packed bf16 pair
  unsigned r; asm("v_cvt_pk_bf16_f32 %0, %1, %2" : "=v"(r) : "v"(lo), "v"(hi)); return r;
}
__device__ __forceinline__ f32x2 pkmul(f32x2 a, f32x2 b){  // packed fp32 dual mul
  f32x2 r; asm("v_pk_mul_f32 %0, %1, %2" : "=v"(r) : "v"(a), "v"(b)); return r;
}

// ---------------- pack adjacency -> word-transposed bitmask ----------------
__global__ __launch_bounds__(256) void pack_adj_k(const int* __restrict__ adj, unsigned* __restrict__ bmT){
  int gid = blockIdx.x*256 + threadIdx.x;
  int lane = threadIdx.x & 63;
  unsigned long long m = __ballot(adj[gid] > 0);
  int w = gid >> 5, i = w >> 7, jw = w & 127;
  if (lane == 0)       bmT[(size_t)jw*NN + i] = (unsigned)m;
  else if (lane == 32) bmT[(size_t)jw*NN + i] = (unsigned)(m >> 32);
}

// ---------------- WbT[h][o][k] = bf16(W[h][k][o]) ----------------
__global__ __launch_bounds__(256) void cast_W_k(const float* __restrict__ W, unsigned short* __restrict__ WbT){
  __shared__ float T[64][65];
  const int h = blockIdx.y, k0 = blockIdx.x*64, t = threadIdx.x;
  for (int idx = t; idx < 1024; idx += 256){
    int k = idx >> 4, c4 = idx & 15;
    *(float4*)&T[k][c4*4] = *(const float4*)&W[((size_t)h*F_IN + k0 + k)*HID + c4*4];
  }
  __syncthreads();
  for (int idx = t; idx < 512; idx += 256){
    int o = idx >> 3, ch = idx & 7;
    s16x8 v;
    #pragma unroll
    for (int e = 0; e < 8; ++e) v[e] = (short)f2bf(T[ch*8 + e][o]);
    *(s16x8*)&WbT[((size_t)h*HID + o)*F_IN + k0 + ch*8] = v;
  }
}

// ---------------- WoT[c][k] = bf16(W_out[k][c]), rows 40..47 zero ----------------
__global__ __launch_bounds__(256) void cast_Wo_k(const float* __restrict__ Wout, unsigned short* __restrict__ WoT){
  int idx = blockIdx.x*256 + threadIdx.x;   // 48*512
  int cc = idx >> 9, k = idx & 511;
  WoT[idx] = (cc < NCLS) ? f2bf(Wout[(size_t)k*NCLS + cc]) : (unsigned short)0;
}

// ---------------- gemm1: WhT[h][o][n] bf16 = (x@W)^T ; srcv/dstv fused epilogue ----------------
__global__ __launch_bounds__(256) void gemm1_k(const float* __restrict__ x,
    const unsigned short* __restrict__ WbT, unsigned short* __restrict__ WhT,
    const float* __restrict__ a_src, const float* __restrict__ a_dst,
    float* __restrict__ srcv, float* __restrict__ dstv){
  __shared__ unsigned short xS[64*64];
  __shared__ unsigned short wS[64*64];
  const int t = threadIdx.x, l = t & 63, wv = t >> 6, g = l >> 4, c = l & 15;
  const int h = blockIdx.y, n0 = blockIdx.x * 64;
  f32x4 acc[4] = {};
  for (int k0 = 0; k0 < F_IN; k0 += 64){
    __syncthreads();
    #pragma unroll
    for (int p = 0; p < 4; ++p){
      int idx = t + p*256, row = idx >> 4, c4 = idx & 15;
      float4 v = *(const float4*)&x[(size_t)(n0+row)*F_IN + k0 + c4*4];
      *(uint2*)&xS[SWZ(row, c4*4)] = make_uint2(cvtpk(v.x, v.y), cvtpk(v.z, v.w));
    }
    #pragma unroll
    for (int p = 0; p < 2; ++p){
      int idx = t + p*256, o = idx >> 3, ch = idx & 7;
      *(s16x8*)&wS[SWZ(o, ch*8)] = *(const s16x8*)&WbT[(size_t)(h*HID + o)*F_IN + k0 + ch*8];
    }
    __syncthreads();
    #pragma unroll
    for (int ks = 0; ks < 2; ++ks){
      s16x8 av = *(const s16x8*)&xS[SWZ(wv*16 + c, ks*32 + g*8)];
      #pragma unroll
      for (int ct = 0; ct < 4; ++ct){
        s16x8 bv = *(const s16x8*)&wS[SWZ(ct*16 + c, ks*32 + g*8)];
        acc[ct] = __builtin_amdgcn_mfma_f32_16x16x32_bf16(av, bv, acc[ct], 0, 0, 0);
      }
    }
  }
  float asv[4], adv[4];
  #pragma unroll
  for (int ct = 0; ct < 4; ++ct){ asv[ct] = a_src[h*HID + ct*16 + c]; adv[ct] = a_dst[h*HID + ct*16 + c]; }
  #pragma unroll
  for (int r = 0; r < 4; ++r){
    float ps = acc[0][r]*asv[0] + acc[1][r]*asv[1] + acc[2][r]*asv[2] + acc[3][r]*asv[3];
    float pd = acc[0][r]*adv[0] + acc[1][r]*adv[1] + acc[2][r]*adv[2] + acc[3][r]*adv[3];
    #pragma unroll
    for (int off = 1; off < 16; off <<= 1){ ps += __shfl_xor(ps, off); pd += __shfl_xor(pd, off); }
    if (c == 0){ int n = n0 + wv*16 + g*4 + r; srcv[h*NN + n] = ps; dstv[h*NN + n] = pd; }
  }
  __syncthreads();
  #pragma unroll
  for (int ct = 0; ct < 4; ++ct)
    *(uint2*)&xS[SWZ(ct*16 + c, wv*16 + g*4)] = make_uint2(cvtpk(acc[ct][0], acc[ct][1]), cvtpk(acc[ct][2], acc[ct][3]));
  __syncthreads();
  #pragma unroll
  for (int p = 0; p < 2; ++p){
    int idx = t + p*256, o = idx >> 3, ch = idx & 7;
    *(s16x8*)&WhT[(size_t)(h*HID + o)*NN + n0 + ch*8] = *(const s16x8*)&xS[SWZ(o, ch*8)];
  }
}

// ---------------- per-4096-segment max reduce ----------------
__global__ __launch_bounds__(256) void maxred_k(const float* __restrict__ in, float* __restrict__ out){
  __shared__ float red[4];
  const float* p = in + (size_t)blockIdx.x*NN;
  float m = -3.0e38f;
  for (int i = threadIdx.x; i < NN; i += 256) m = fmaxf(m, p[i]);
  #pragma unroll
  for (int off = 32; off; off >>= 1) m = fmaxf(m, __shfl_xor(m, off));
  if ((threadIdx.x & 63) == 0) red[threadIdx.x >> 6] = m;
  __syncthreads();
  if (threadIdx.x == 0) out[blockIdx.x] = fmaxf(fmaxf(red[0], red[1]), fmaxf(red[2], red[3]));
}

// ---------------- MFMA masked-softmax aggregate (factorized P, ping-pong single-barrier) ----------------
// Block: 32 rows x one head; 4 waves = j-parity tl(2) x row-half rH(2).
// Per iteration: loadRegs(next) -> compute(buf[cur]) -> writeLDS(buf[cur^1]) -> barrier.
// p_ij = bit * med3(A_i*B_j, C_i*D_j, 1); (B,D) staged in dS. Row sums via ones-MFMA.
template<int NCT, int NJT, bool CHUNKED, bool DO_ELU>
__global__ __launch_bounds__(256) void agg_mfma_k(
    const unsigned* __restrict__ bmT, const unsigned short* __restrict__ VT,
    const float* __restrict__ srcv, const float* __restrict__ dstv,
    const float* __restrict__ maxp, void* __restrict__ outp)
{
  __shared__ unsigned short vS[2][2][NCT*16*64];
  __shared__ float2 dS[2][2][64];
  __shared__ unsigned bitS[2][2][2][32];
  const int t = threadIdx.x, l = t & 63, wv = t >> 6, g = l >> 4, c = l & 15;
  const int h   = CHUNKED ? 0 : blockIdx.y;
  const int jt0 = CHUNKED ? blockIdx.y * NJT : 0;
  const int i0 = blockIdx.x * 32;
  const int tl = wv >> 1, rH = wv & 1;
  const int lr = rH*16 + c;
  const float sr = srcv[h*NN + i0 + lr];
  const float mx = maxp[CHUNKED ? 0 : h];
  const float tm = sr + mx;
  const float mi2 = fmaxf(tm, 0.2f*tm) * LOG2E;
  f32x2 ac2;
  ac2[0] = exp2f(fmaf(sr, LOG2E, -mi2));        // A_i
  ac2[1] = exp2f(fmaf(0.2f*sr, LOG2E, -mi2));   // C_i
  const unsigned short* vb = VT + (size_t)h*HID*NN;

  f32x4 acc[NCT] = {};
  f32x4 accs = {};
  s16x8 ones;
  #pragma unroll
  for (int e = 0; e < 8; ++e) ones[e] = (short)0x3F80;

  s16x8 vreg[NCT]; float2 dreg = make_float2(0.f, 0.f); unsigned breg = 0;
  auto loadRegs = [&](int jt){
    #pragma unroll
    for (int p = 0; p < NCT; ++p){
      int u = t + p*256;
      int tt = u / (NCT*128), rem = u % (NCT*128);
      int o = rem >> 3, chk = rem & 7;
      vreg[p] = *(const s16x8*)&vb[(size_t)o*NN + (jt+tt)*64 + chk*8];
    }
    if (t < 128){
      float d = dstv[h*NN + (jt + (t>>6))*64 + (t&63)];
      dreg = make_float2(exp2f(d*LOG2E), exp2f(0.2f*d*LOG2E));
    }
    else { int u = t - 128; breg = bmT[(size_t)((jt + (u>>6))*2 + ((u>>5)&1))*NN + i0 + (u&31)]; }
  };
  auto writeLDS = [&](int b){
    #pragma unroll
    for (int p = 0; p < NCT; ++p){
      int u = t + p*256;
      int tt = u / (NCT*128), rem = u % (NCT*128);
      int o = rem >> 3, chk = rem & 7;
      *(s16x8*)&vS[b][tt][SWZ(o, chk*8)] = vreg[p];
    }
    if (t < 128) dS[b][t>>6][t&63] = dreg;
    else { int u = t - 128; bitS[b][u>>6][(u>>5)&1][u&31] = breg; }
  };
  auto computeBuf = [&](int b){
    #pragma unroll
    for (int ks = 0; ks < 2; ++ks){
      unsigned wb = (bitS[b][tl][ks][lr] >> (g*8)) & 0xffu;
      const f32x2* dr = (const f32x2*)&dS[b][tl][ks*32 + g*8];
      float q[8];
      #pragma unroll
      for (int e = 0; e < 8; ++e){
        f32x2 pr = pkmul(ac2, dr[e]);
        float m3 = __builtin_amdgcn_fmed3f(pr[0], pr[1], 1.0f);
        q[e] = (wb & (1u << e)) ? m3 : 0.f;
      }
      s16x8 af;
      ((unsigned*)&af)[0] = cvtpk(q[0], q[1]);
      ((unsigned*)&af)[1] = cvtpk(q[2], q[3]);
      ((unsigned*)&af)[2] = cvtpk(q[4], q[5]);
      ((unsigned*)&af)[3] = cvtpk(q[6], q[7]);
      #pragma unroll
      for (int ct = 0; ct < NCT; ++ct){
        s16x8 bv = *(const s16x8*)&vS[b][tl][SWZ(ct*16 + c, ks*32 + g*8)];
        acc[ct] = __builtin_amdgcn_mfma_f32_16x16x32_bf16(af, bv, acc[ct], 0, 0, 0);
      }
      accs = __builtin_amdgcn_mfma_f32_16x16x32_bf16(af, ones, accs, 0, 0, 0);
    }
  };

  // prologue: stage first pair into buf 0
  loadRegs(jt0);
  writeLDS(0);
  __syncthreads();
  int cur = 0;
  for (int jj = 0; jj < NJT; jj += 2){
    const bool more = (jj + 2 < NJT);
    if (more) loadRegs(jt0 + jj + 2);   // issue globals early
    computeBuf(cur);                    // hide latency under MFMA+VALU
    if (more) writeLDS(cur ^ 1);        // write-late into other buffer
    __syncthreads();                    // single barrier per iteration
    cur ^= 1;
  }

  // merge j-parity wave pairs via LDS (aliases vS)
  float* mrg = (float*)&vS[0][0][0];
  constexpr int S = (NCT + 1) * 4;
  if (tl == 1){
    int base = (rH*64 + l) * S;
    #pragma unroll
    for (int ct = 0; ct < NCT; ++ct)
      #pragma unroll
      for (int r = 0; r < 4; ++r) mrg[base + ct*4 + r] = acc[ct][r];
    #pragma unroll
    for (int r = 0; r < 4; ++r) mrg[base + NCT*4 + r] = accs[r];
  }
  __syncthreads();
  if (tl == 0){
    int base = (rH*64 + l) * S;
    #pragma unroll
    for (int ct = 0; ct < NCT; ++ct)
      #pragma unroll
      for (int r = 0; r < 4; ++r) acc[ct][r] += mrg[base + ct*4 + r];
    #pragma unroll
    for (int r = 0; r < 4; ++r) accs[r] += mrg[base + NCT*4 + r];
    if (!CHUNKED){
      unsigned short* ob = (unsigned short*)outp;
      #pragma unroll
      for (int r = 0; r < 4; ++r){
        float inv = 1.f / fmaxf(accs[r], 1e-30f);
        int row = i0 + rH*16 + g*4 + r;
        #pragma unroll
        for (int ct = 0; ct < NCT; ++ct){
          float v = acc[ct][r] * inv;
          if (DO_ELU) v = v > 0.f ? v : __expf(v) - 1.f;
          ob[(size_t)row*(NHEAD*HID) + h*HID + ct*16 + c] = f2bf(v);
        }
      }
    } else {
      float* ob = (float*)outp + (size_t)blockIdx.y * NN * 64;
      #pragma unroll
      for (int r = 0; r < 4; ++r){
        int row = i0 + rH*16 + g*4 + r;
        #pragma unroll
        for (int ct = 0; ct < NCT; ++ct)
          ob[(size_t)row*64 + ct*16 + c] = acc[ct][r];
        if (c == 0) ob[(size_t)row*64 + 48] = accs[r];
      }
    }
  }
}

// ---------------- gemm2: WhT2[c][n] bf16 = (h_bf16 @ W_out)^T ; s2/d2 fused ----------------
__global__ __launch_bounds__(256) void gemm2_k(const unsigned short* __restrict__ hb,
    const unsigned short* __restrict__ WoT, const float* __restrict__ aos, const float* __restrict__ aod,
    unsigned short* __restrict__ WhT2, float* __restrict__ s2, float* __restrict__ d2){
  __shared__ unsigned short aS[64*64];
  __shared__ unsigned short bS[48*64];
  const int t = threadIdx.x, l = t & 63, wv = t >> 6, g = l >> 4, c = l & 15;
  const int n0 = blockIdx.x * 64;
  f32x4 acc[3] = {};
  for (int k0 = 0; k0 < NHEAD*HID; k0 += 64){
    __syncthreads();
    #pragma unroll
    for (int p = 0; p < 2; ++p){
      int u = t + p*256, o = u >> 3, ch = u & 7;
      *(s16x8*)&aS[SWZ(o, ch*8)] = *(const s16x8*)&hb[(size_t)(n0+o)*(NHEAD*HID) + k0 + ch*8];
    }
    for (int u = t; u < 384; u += 256){
      int o = u >> 3, ch = u & 7;
      *(s16x8*)&bS[SWZ(o, ch*8)] = *(const s16x8*)&WoT[(size_t)o*(NHEAD*HID) + k0 + ch*8];
    }
    __syncthreads();
    #pragma unroll
    for (int ks = 0; ks < 2; ++ks){
      s16x8 av = *(const s16x8*)&aS[SWZ(wv*16 + c, ks*32 + g*8)];
      #pragma unroll
      for (int ct = 0; ct < 3; ++ct){
        s16x8 bv = *(const s16x8*)&bS[SWZ(ct*16 + c, ks*32 + g*8)];
        acc[ct] = __builtin_amdgcn_mfma_f32_16x16x32_bf16(av, bv, acc[ct], 0, 0, 0);
      }
    }
  }
  float asv[3], adv[3];
  #pragma unroll
  for (int ct = 0; ct < 3; ++ct){
    int col = ct*16 + c;
    asv[ct] = (col < NCLS) ? aos[col] : 0.f;
    adv[ct] = (col < NCLS) ? aod[col] : 0.f;
  }
  #pragma unroll
  for (int r = 0; r < 4; ++r){
    float ps = acc[0][r]*asv[0] + acc[1][r]*asv[1] + acc[2][r]*asv[2];
    float pd = acc[0][r]*adv[0] + acc[1][r]*adv[1] + acc[2][r]*adv[2];
    #pragma unroll
    for (int off = 1; off < 16; off <<= 1){ ps += __shfl_xor(ps, off); pd += __shfl_xor(pd, off); }
    if (c == 0){ int n = n0 + wv*16 + g*4 + r; s2[n] = ps; d2[n] = pd; }
  }
  __syncthreads();
  #pragma unroll
  for (int ct = 0; ct < 3; ++ct)
    *(uint2*)&bS[SWZ(ct*16 + c, wv*16 + g*4)] = make_uint2(cvtpk(acc[ct][0], acc[ct][1]), cvtpk(acc[ct][2], acc[ct][3]));
  __syncthreads();
  for (int u = t; u < 384; u += 256){
    int o = u >> 3, ch = u & 7;
    *(s16x8*)&WhT2[(size_t)o*NN + n0 + ch*8] = *(const s16x8*)&bS[SWZ(o, ch*8)];
  }
}

// ---------------- merge 8 chunks + elu + row log_softmax ----------------
__global__ __launch_bounds__(256) void final_k(const float* __restrict__ part, float* __restrict__ out){
  const int wid = (blockIdx.x*256 + threadIdx.x) >> 6;
  const int c = threadIdx.x & 63;
  float acc = 0.f, rs = 0.f;
  #pragma unroll
  for (int ch = 0; ch < 8; ++ch){
    const float* pb = part + ((size_t)ch*NN + wid)*64;
    if (c < 48) acc += pb[c];
    rs += pb[48];
  }
  float v = acc / fmaxf(rs, 1e-30f);
  float e = v > 0.f ? v : __expf(v) - 1.f;
  float ev = (c < NCLS) ? e : -3.0e38f;
  float m = ev;
  #pragma unroll
  for (int off = 32; off; off >>= 1) m = fmaxf(m, __shfl_xor(m, off));
  float ex = (c < NCLS) ? __expf(e - m) : 0.f;
  float s = ex;
  #pragma unroll
  for (int off = 32; off; off >>= 1) s += __shfl_xor(s, off);
  if (c < NCLS) out[(size_t)wid*NCLS + c] = e - m - __logf(s);
}

extern "C" void kernel_launch(void* const* d_in, const int* in_sizes, int n_in,
                              void* d_out, int out_size, void* d_ws, size_t ws_size,
                              hipStream_t stream){
  (void)in_sizes; (void)n_in; (void)out_size; (void)ws_size;
  const float* x     = (const float*)d_in[0];
  const int*   adj   = (const int*)  d_in[1];
  const float* W     = (const float*)d_in[2];
  const float* a_src = (const float*)d_in[3];
  const float* a_dst = (const float*)d_in[4];
  const float* W_out = (const float*)d_in[5];
  const float* aos   = (const float*)d_in[6];
  const float* aod   = (const float*)d_in[7];
  float* out = (float*)d_out;

  char* p = (char*)d_ws;
  unsigned* bmT        = (unsigned*)p;       p += (size_t)NN*128*4;            // 2 MB
  unsigned short* WbT  = (unsigned short*)p; p += (size_t)NHEAD*HID*F_IN*2;    // 1 MB
  unsigned short* WhT  = (unsigned short*)p; p += (size_t)NHEAD*HID*NN*2;      // 4 MB
  unsigned short* hbuf = (unsigned short*)p; p += (size_t)NN*NHEAD*HID*2;      // 4 MB
  unsigned short* WoT  = (unsigned short*)p; p += (size_t)48*NHEAD*HID*2;      // 48 KB
  unsigned short* WhT2 = (unsigned short*)p; p += (size_t)48*NN*2;             // 384 KB
  float* srcv = (float*)p; p += (size_t)NHEAD*NN*4;
  float* dstv = (float*)p; p += (size_t)NHEAD*NN*4;
  float* maxd = (float*)p; p += 256;
  float* s2   = (float*)p; p += (size_t)NN*4;
  float* d2   = (float*)p; p += (size_t)NN*4;
  float* m2   = (float*)p; p += 256;
  float* part = (float*)p; p += (size_t)8*NN*64*4;                             // 8 MB

  pack_adj_k<<<(NN*NN)/256, 256, 0, stream>>>(adj, bmT);
  cast_W_k<<<dim3(F_IN/64, NHEAD), 256, 0, stream>>>(W, WbT);
  cast_Wo_k<<<96, 256, 0, stream>>>(W_out, WoT);
  gemm1_k<<<dim3(NN/64, NHEAD), 256, 0, stream>>>(x, WbT, WhT, a_src, a_dst, srcv, dstv);
  maxred_k<<<NHEAD, 256, 0, stream>>>(dstv, maxd);
  agg_mfma_k<4, 64, false, true><<<dim3(NN/32, NHEAD), 256, 0, stream>>>(bmT, WhT, srcv, dstv, maxd, hbuf);
  gemm2_k<<<NN/64, 256, 0, stream>>>(hbuf, WoT, aos, aod, WhT2, s2, d2);
  maxred_k<<<1, 256, 0, stream>>>(d2, m2);
  agg_mfma_k<3, 8, true, false><<<dim3(NN/32, 8), 256, 0, stream>>>(bmT, WhT2, s2, d2, m2, part);
  final_k<<<NN/4, 256, 0, stream>>>(part, out);
}